// Round 8
// baseline (1021.191 us; speedup 1.0000x reference)
//
#include <hip/hip_runtime.h>
#include <hip/hip_fp16.h>

#define NTOK 1024
#define INF  1024
#define NH   16
#define DH   64
#define BDIM 512
#define NMEM 8192
#define OUTF 1024
#define NWRD 16   // 512 bits = 16 u32

typedef _Float16 f16x8 __attribute__((ext_vector_type(8)));
typedef float    f32x4 __attribute__((ext_vector_type(4)));
typedef int      i32x4 __attribute__((ext_vector_type(4)));

#define GLOAD16(G, L) __builtin_amdgcn_global_load_lds( \
    (const __attribute__((address_space(1))) unsigned int*)(G), \
    (__attribute__((address_space(3))) unsigned int*)(L), 16, 0, 0)

// score/TEMP * log2(e):  cos(pi/2*(1-s/512)) == sin(pi/2 * s/512), s = count
__device__ inline float score2(float s) {
  return 144.2695040889f * __sinf(s * 0.0030679615757712823f);
}

// ---------------- K1: q = x @ Wq^T + bq (f32, 64x64 tile) ----------------
__global__ __launch_bounds__(256) void k_qgemm(const float* __restrict__ x,
    const float* __restrict__ Wq, const float* __restrict__ bq, float* __restrict__ q) {
  __shared__ float As[64][17];
  __shared__ float Bs[64][17];
  const int tx = threadIdx.x & 15, ty = threadIdx.x >> 4;
  const int n0 = blockIdx.y * 64, o0 = blockIdx.x * 64;
  const int r = threadIdx.x >> 2, c4 = (threadIdx.x & 3) * 4;
  float acc[4][4] = {};
  for (int k0 = 0; k0 < INF; k0 += 16) {
    float4 av = *(const float4*)&x[(size_t)(n0 + r) * INF + k0 + c4];
    float4 bv = *(const float4*)&Wq[(size_t)(o0 + r) * INF + k0 + c4];
    __syncthreads();               // prev compute done before LDS overwrite
    As[r][c4+0] = av.x; As[r][c4+1] = av.y; As[r][c4+2] = av.z; As[r][c4+3] = av.w;
    Bs[r][c4+0] = bv.x; Bs[r][c4+1] = bv.y; Bs[r][c4+2] = bv.z; Bs[r][c4+3] = bv.w;
    __syncthreads();
    #pragma unroll
    for (int kk = 0; kk < 16; ++kk) {
      float a[4], b[4];
      #pragma unroll
      for (int i = 0; i < 4; ++i) a[i] = As[ty*4+i][kk];
      #pragma unroll
      for (int j = 0; j < 4; ++j) b[j] = Bs[tx*4+j][kk];
      #pragma unroll
      for (int i = 0; i < 4; ++i)
        #pragma unroll
        for (int j = 0; j < 4; ++j) acc[i][j] += a[i] * b[j];
    }
  }
  #pragma unroll
  for (int i = 0; i < 4; ++i) {
    const int row = n0 + ty*4 + i;
    #pragma unroll
    for (int j = 0; j < 4; ++j) {
      const int col = o0 + tx*4 + j;
      q[(size_t)row * OUTF + col] = acc[i][j] + bq[col];
    }
  }
}

// ---------------- K2: code_i8 = sign(q . bin_proj) as +-1 i8 ---------------
// norm of q doesn't change sign -> skip normalization entirely
__global__ __launch_bounds__(256) void k_code(const float* __restrict__ q,
    const float* __restrict__ bp, signed char* __restrict__ code_i8) {
  const int h = blockIdx.y, n0 = blockIdx.x * 16;
  __shared__ float ql[16][68];
  const int t = threadIdx.x;
  {
    const int r = t >> 4, c = (t & 15) * 4;
    float4 v = *(const float4*)&q[(size_t)(n0 + r) * OUTF + h * 64 + c];
    ql[r][c] = v.x; ql[r][c+1] = v.y; ql[r][c+2] = v.z; ql[r][c+3] = v.w;
  }
  __syncthreads();
  #pragma unroll
  for (int bb = 0; bb < 512; bb += 256) {
    const int b = bb + t;
    float bpv[64];
    const float4* src = (const float4*)&bp[((size_t)h * BDIM + b) * 64];
    #pragma unroll
    for (int j = 0; j < 16; ++j) {
      float4 v = src[j];
      bpv[j*4] = v.x; bpv[j*4+1] = v.y; bpv[j*4+2] = v.z; bpv[j*4+3] = v.w;
    }
    for (int n = 0; n < 16; ++n) {
      float dot = 0.f;
      #pragma unroll
      for (int d = 0; d < 64; ++d) dot += bpv[d] * ql[n][d];
      code_i8[((size_t)h * NTOK + n0 + n) * BDIM + b] = dot > 0.f ? 1 : -1;
    }
  }
}

// -------- K3: weight_matrix -> sign bits (for k_wt) AND +-1 i8 -------------
__global__ __launch_bounds__(256) void k_packw(const float* __restrict__ w,
    unsigned* __restrict__ wp, signed char* __restrict__ w_i8) {
  const int row  = blockIdx.x * 4 + (threadIdx.x >> 6);
  const int lane = threadIdx.x & 63;
  const float* src = w + (size_t)row * BDIM;
  unsigned my = 0;
  #pragma unroll
  for (int kk = 0; kk < 8; ++kk) {
    float v = src[kk * 64 + lane];
    w_i8[(size_t)row * BDIM + kk * 64 + lane] = v > 0.f ? 1 : -1;
    unsigned long long m = __ballot(v > 0.f);
    if ((lane >> 1) == kk) my = (lane & 1) ? (unsigned)(m >> 32) : (unsigned)m;
  }
  if (lane < 16) wp[(size_t)row * NWRD + lane] = my;
}

// ---------------- K3b: transpose bin_inv [h][d][b] -> binT [h][b][d] -------
__global__ __launch_bounds__(256) void k_binT(const float* __restrict__ binv,
                                              float* __restrict__ bT) {
  const int h = blockIdx.y, b0 = blockIdx.x * 64;
  __shared__ float tl[64][65];
  const int t = threadIdx.x;
  #pragma unroll
  for (int i = 0; i < 4; ++i) {
    int fi = t + 256 * i;
    int d = fi >> 4, b = (fi & 15) * 4;
    float4 v = *(const float4*)&binv[((size_t)h * DH + d) * BDIM + b0 + b];
    tl[d][b] = v.x; tl[d][b+1] = v.y; tl[d][b+2] = v.z; tl[d][b+3] = v.w;
  }
  __syncthreads();
  #pragma unroll
  for (int i = 0; i < 4; ++i) {
    int fo = t + 256 * i;
    int bb = fo >> 4, dd = (fo & 15) * 4;
    float4 v = { tl[dd][bb], tl[dd+1][bb], tl[dd+2][bb], tl[dd+3][bb] };
    *(float4*)&bT[((size_t)h * BDIM + b0 + bb) * DH + dd] = v;
  }
}

// ------- K4: expand bits -> f16 wt [hg][b][m] (+-1), PRE-SWIZZLED ----------
// Within each 128B (64-m) window, 16B chunk g stores logical chunk g^(b&7),
// so stageF's linear global_load_lds + swizzled ds_read are conflict-free.
__global__ __launch_bounds__(256) void k_wt(const unsigned* __restrict__ wp,
    unsigned short* __restrict__ wt, int h0) {
  const int hg = blockIdx.z, h = h0 + hg;
  const int b0 = blockIdx.y * 64, m0 = blockIdx.x * 256;
  __shared__ unsigned bits[256][2];
  const int t = threadIdx.x;
  const unsigned* src = wp + (size_t)(h * NMEM + m0 + t) * NWRD + (b0 >> 5);
  bits[t][0] = src[0]; bits[t][1] = src[1];
  __syncthreads();
  const int b = t >> 2, ms = (t & 3) * 64;
  const int wd = b >> 5, sh = b & 31;
  const int bx7 = b & 7;
  unsigned short* dst = wt + ((size_t)hg * BDIM + b0 + b) * NMEM + m0 + ms;
  #pragma unroll
  for (int g = 0; g < 8; ++g) {
    const int pg = g ^ bx7;
    const int j = ms + g * 8;
    ushort4 v0, v1;
    v0.x = ((bits[j+0][wd] >> sh) & 1) ? 0x3C00 : 0xBC00;
    v0.y = ((bits[j+1][wd] >> sh) & 1) ? 0x3C00 : 0xBC00;
    v0.z = ((bits[j+2][wd] >> sh) & 1) ? 0x3C00 : 0xBC00;
    v0.w = ((bits[j+3][wd] >> sh) & 1) ? 0x3C00 : 0xBC00;
    v1.x = ((bits[j+4][wd] >> sh) & 1) ? 0x3C00 : 0xBC00;
    v1.y = ((bits[j+5][wd] >> sh) & 1) ? 0x3C00 : 0xBC00;
    v1.z = ((bits[j+6][wd] >> sh) & 1) ? 0x3C00 : 0xBC00;
    v1.w = ((bits[j+7][wd] >> sh) & 1) ? 0x3C00 : 0xBC00;
    *(ushort4*)&dst[pg * 8]     = v0;
    *(ushort4*)&dst[pg * 8 + 4] = v1;
  }
}

// ------- K5: sim = code @ w^T via i8 MFMA 16x16x64 + in-place exp tail -----
// TLP-first: 16 rows/block, 256 thr (4 waves), afrag in 32 VGPRs -> ~100
// VGPR total, launch_bounds(256,4) => 4 waves/SIMD. All same-head blocks on
// one XCD (head-fast), streaming m in the same order (convoy L2 sharing).
// Tail: re-read own 16x8192 sim slice (L2-hot), p = exp2(sct[s]-sm), write
// f16 in-place, pre-swizzled chunks (g -> g^(row&7)) for stageF.
// Softmax 1/Z cancels in the later per-head L2-normalize -> numerator only.
__global__ __launch_bounds__(256, 4) void k_sim(const signed char* __restrict__ code_i8,
    const signed char* __restrict__ w_i8, short* __restrict__ simb,
    int h0, int gmask, int gshift) {
  const int bid = (int)blockIdx.x;
  const int hg = bid & gmask, h = h0 + hg;      // XCD = bid%8 = h%8
  const int n0 = (bid >> gshift) * 16;
  const int t = threadIdx.x, lane = t & 63, wid = t >> 6;   // 4 waves
  __shared__ int smaxl[16];
  __shared__ float sct[513];
  if (t < 16) smaxl[t] = -(1 << 30);
  for (int p = t; p < 513; p += 256)
    sct[p] = score2(2.f * (float)p - 512.f);
  // A frag: row = n0 + (lane&15), k = kk*64 + (lane>>4)*16  (32 VGPRs)
  i32x4 afrag[8];
  #pragma unroll
  for (int kk = 0; kk < 8; ++kk)
    afrag[kk] = *(const i32x4*)(code_i8 +
        ((size_t)h * NTOK + n0 + (lane & 15)) * BDIM + kk * 64 + (lane >> 4) * 16);
  __syncthreads();
  int vmax[4] = {-(1 << 30), -(1 << 30), -(1 << 30), -(1 << 30)};
  const signed char* bbase = w_i8 + (size_t)h * NMEM * BDIM +
                             (size_t)(lane & 15) * BDIM + (lane >> 4) * 16;
  short* srow = simb + ((size_t)hg * NTOK + n0) * NMEM;
  for (int i = 0; i < 128; ++i) {
    const int m0 = (i * 4 + wid) * 16;           // wave-interleaved m-tiles
    const signed char* bb = bbase + (size_t)m0 * BDIM;
    i32x4 acc = {};
    #pragma unroll
    for (int kk = 0; kk < 8; ++kk) {
      i32x4 b0 = *(const i32x4*)(bb + kk * 64);
      acc = __builtin_amdgcn_mfma_i32_16x16x64_i8(afrag[kk], b0, acc, 0, 0, 0);
    }
    #pragma unroll
    for (int j = 0; j < 4; ++j) {
      const int row = (lane >> 4) * 4 + j;       // C: row=(l>>4)*4+reg
      srow[(size_t)row * NMEM + m0 + (lane & 15)] = (short)acc[j];  // col=l&15
      vmax[j] = max(vmax[j], acc[j]);
    }
  }
  #pragma unroll
  for (int j = 0; j < 4; ++j) {
    int v = vmax[j];
    #pragma unroll
    for (int s = 1; s < 16; s <<= 1) v = max(v, __shfl_xor(v, s));
    if ((lane & 15) == 0)
      atomicMax(&smaxl[(lane >> 4) * 4 + j], v);
  }
  __syncthreads();   // smaxl final, all sim stores done (wg-scope visibility)
  unsigned short* arow = (unsigned short*)srow;
  for (int it = 0; it < 8; ++it) {
    const int gw = it * 256 + t;               // window id in [0, 2048)
    const int row = gw >> 7, win = gw & 127;   // 128 x 64-elem windows per row
    const float sm2 = sct[(smaxl[row] + 512) >> 1];
    const short* sp = srow + (size_t)row * NMEM + win * 64;
    uint4 sv[8];
    #pragma unroll
    for (int c = 0; c < 8; ++c) sv[c] = *(const uint4*)(sp + c * 8);
    const int rx = row & 7;                    // global row &7 == local (n0%16==0)
    unsigned short* dp = arow + (size_t)row * NMEM + win * 64;
    #pragma unroll
    for (int c = 0; c < 8; ++c) {
      unsigned ov[4];
      #pragma unroll
      for (int k = 0; k < 4; ++k) {
        const unsigned w2 = (&sv[c].x)[k];
        const int lo = (int)(short)(w2 & 0xffffu);
        const int hi = (int)(short)(w2 >> 16);
        float p0 = exp2f(sct[(lo + 512) >> 1] - sm2);
        float p1 = exp2f(sct[(hi + 512) >> 1] - sm2);
        ov[k] = (unsigned)__half_as_ushort(__float2half(p0))
              | ((unsigned)__half_as_ushort(__float2half(p1)) << 16);
      }
      *(uint4*)(dp + (c ^ rx) * 8) = make_uint4(ov[0], ov[1], ov[2], ov[3]);
    }
  }
}

// ------- K6: o1^T = (attn @ wt)^T, pure f16 MFMA GEMM, 128x128 tile --------
// Both operands pre-swizzled in global; linear global_load_lds staging;
// XOR-deswizzled ds_read_b128 (conflict-free, verified R5: BANK_CONFLICT=0).
__global__ __launch_bounds__(512, 2) void k_stageF(const unsigned short* __restrict__ attn,
    const unsigned short* __restrict__ wt, float* __restrict__ o1t,
    int gmask, int gshift) {
  __shared__ _Float16 Al[128][64];
  __shared__ _Float16 Bl[128][64];
  const int wg = (int)blockIdx.x;
  const int hg = wg & gmask;                   // XCD = wg%8 = hg%8
  const int rest = wg >> gshift;
  const int nt = rest & 7, bt = rest >> 3;
  const int n0 = nt * 128, b0 = bt * 128;
  const int t = threadIdx.x;
  const int lane = t & 63, wid = t >> 6;
  const int wm = wid >> 2, wn = wid & 3;
  f32x4 acc[4][2];
  #pragma unroll
  for (int i = 0; i < 4; ++i)
    #pragma unroll
    for (int j = 0; j < 2; ++j) acc[i][j] = (f32x4){0.f, 0.f, 0.f, 0.f};

  const unsigned short* ag = attn + ((size_t)hg * NTOK + n0 + 16*wid + (lane >> 3)) * NMEM + (lane & 7) * 8;
  const unsigned short* bg = wt   + ((size_t)hg * BDIM + b0 + 16*wid + (lane >> 3)) * NMEM + (lane & 7) * 8;
  _Float16* al0 = &Al[16 * wid][0];            // wave-uniform LDS bases
  _Float16* bl0 = &Bl[16 * wid][0];

  for (int k0 = 0; k0 < NMEM; k0 += 64) {
    __syncthreads();                    // previous tile fully consumed
    GLOAD16(ag + k0,            al0);
    GLOAD16(ag + k0 + 8 * NMEM, al0 + 8 * 64);
    GLOAD16(bg + k0,            bl0);
    GLOAD16(bg + k0 + 8 * NMEM, bl0 + 8 * 64);
    __syncthreads();                    // drains vmcnt -> tile ready
    #pragma unroll
    for (int kk = 0; kk < 64; kk += 32) {
      const int phys = (((kk >> 3) + (lane >> 4)) ^ (lane & 7)) * 8;
      f16x8 af[4], bf[2];
      #pragma unroll
      for (int fm = 0; fm < 4; ++fm)
        af[fm] = *(const f16x8*)&Al[wm*64 + fm*16 + (lane & 15)][phys];
      #pragma unroll
      for (int fn = 0; fn < 2; ++fn)
        bf[fn] = *(const f16x8*)&Bl[wn*32 + fn*16 + (lane & 15)][phys];
      #pragma unroll
      for (int fm = 0; fm < 4; ++fm)
        #pragma unroll
        for (int fn = 0; fn < 2; ++fn)
          acc[fm][fn] = __builtin_amdgcn_mfma_f32_16x16x32_f16(af[fm], bf[fn], acc[fm][fn], 0, 0, 0);
    }
  }
  #pragma unroll
  for (int fm = 0; fm < 4; ++fm) {
    const int rowb = n0 + wm*64 + fm*16 + (lane >> 4) * 4;   // C: row=(l>>4)*4+reg
    #pragma unroll
    for (int fn = 0; fn < 2; ++fn) {
      const int col = b0 + wn*32 + fn*16 + (lane & 15);      // C: col=l&15
      *(f32x4*)&o1t[((size_t)hg * BDIM + col) * NTOK + rowb] = acc[fm][fn];
    }
  }
}

// ------- K7: out[n][h*64+d] = normalize_d( o1 . bin_inv ) ------------------
__global__ __launch_bounds__(256) void k_proj(const float* __restrict__ o1t,
    const float* __restrict__ bT, float* __restrict__ o2, int h0) {
  const int hg = blockIdx.y, h = h0 + hg;
  const int n0 = blockIdx.x * 64;
  __shared__ float bl[128][68];
  __shared__ float ol[128][68];
  __shared__ float outl[64][68];
  __shared__ float nrm[64];
  const int t = threadIdx.x;
  const int tx = t & 15, ty = t >> 4;
  float acc[4][4] = {};
  for (int c = 0; c < 4; ++c) {
    const int bb0 = c * 128;
    __syncthreads();
    #pragma unroll
    for (int i = 0; i < 8; ++i) {
      int fi = t + 256 * i;
      int rr = fi >> 4, cc = (fi & 15) * 4;
      *(float4*)&bl[rr][cc] = *(const float4*)&bT[((size_t)h * BDIM + bb0 + rr) * DH + cc];
      *(float4*)&ol[rr][cc] = *(const float4*)&o1t[((size_t)hg * BDIM + bb0 + rr) * NTOK + n0 + cc];
    }
    __syncthreads();
    for (int bb = 0; bb < 128; ++bb) {
      float4 bd = *(const float4*)&bl[bb][tx * 4];
      float4 on = *(const float4*)&ol[bb][ty * 4];
      float ai[4] = {on.x, on.y, on.z, on.w};
      float bj[4] = {bd.x, bd.y, bd.z, bd.w};
      #pragma unroll
      for (int i = 0; i < 4; ++i)
        #pragma unroll
        for (int j = 0; j < 4; ++j) acc[i][j] += ai[i] * bj[j];
    }
  }
  __syncthreads();
  #pragma unroll
  for (int i = 0; i < 4; ++i)
    #pragma unroll
    for (int j = 0; j < 4; ++j) outl[ty*4 + i][tx*4 + j] = acc[i][j];
  __syncthreads();
  if (t < 64) {
    float s = 0.f;
    #pragma unroll
    for (int d = 0; d < 64; ++d) { float v = outl[t][d]; s += v * v; }
    nrm[t] = 1.f / sqrtf(s);
  }
  __syncthreads();
  {
    const int n = t >> 2, dg = (t & 3) * 16;
    #pragma unroll
    for (int j = 0; j < 16; ++j)
      o2[(size_t)(n0 + n) * OUTF + h * 64 + dg + j] = outl[n][dg + j] * nrm[n];
  }
}

// ------- K8: LayerNorm over 1024 features ----------------------------------
__global__ __launch_bounds__(256) void k_ln(const float* __restrict__ o2,
    const float* __restrict__ lnw, const float* __restrict__ lnb, float* __restrict__ out) {
  const int n = blockIdx.x, t = threadIdx.x;
  __shared__ float red[4];
  float4 v = *(const float4*)&o2[(size_t)n * OUTF + t * 4];
  float s = v.x + v.y + v.z + v.w;
  const int lane = t & 63, wid = t >> 6;
  #pragma unroll
  for (int off = 32; off; off >>= 1) s += __shfl_down(s, off);
  if (lane == 0) red[wid] = s;
  __syncthreads();
  const float mu = (red[0] + red[1] + red[2] + red[3]) * (1.f / 1024.f);
  float4 d = {v.x - mu, v.y - mu, v.z - mu, v.w - mu};
  float s2 = d.x*d.x + d.y*d.y + d.z*d.z + d.w*d.w;
  #pragma unroll
  for (int off = 32; off; off >>= 1) s2 += __shfl_down(s2, off);
  __syncthreads();
  if (lane == 0) red[wid] = s2;
  __syncthreads();
  const float var = (red[0] + red[1] + red[2] + red[3]) * (1.f / 1024.f);
  const float inv = 1.f / sqrtf(var + 1e-5f);
  float4 w = *(const float4*)&lnw[t * 4];
  float4 b = *(const float4*)&lnb[t * 4];
  float4 o = { d.x*inv*w.x + b.x, d.y*inv*w.y + b.y,
               d.z*inv*w.z + b.z, d.w*inv*w.w + b.w };
  *(float4*)&out[(size_t)n * OUTF + t * 4] = o;
}

extern "C" void kernel_launch(void* const* d_in, const int* in_sizes, int n_in,
                              void* d_out, int out_size, void* d_ws, size_t ws_size,
                              hipStream_t stream) {
  (void)in_sizes; (void)n_in; (void)out_size;
  const float* x    = (const float*)d_in[0];
  const float* Wq   = (const float*)d_in[1];
  const float* bq   = (const float*)d_in[2];
  const float* bp   = (const float*)d_in[3];
  const float* binv = (const float*)d_in[4];
  const float* wm   = (const float*)d_in[5];
  const float* lnw  = (const float*)d_in[6];
  const float* lnb  = (const float*)d_in[7];
  float* outp = (float*)d_out;

  char* ws = (char*)d_ws;
  size_t off = 0;
  auto carve = [&](size_t bytes) -> char* {
    char* p = ws + off;
    off += (bytes + 255) & ~(size_t)255;
    return p;
  };
  float*       q       = (float*)      carve((size_t)NTOK * OUTF * 4);
  signed char* code_i8 = (signed char*)carve((size_t)NH * NTOK * BDIM);
  unsigned*    wpk     = (unsigned*)   carve((size_t)NH * NMEM * NWRD * 4);
  signed char* w_i8    = (signed char*)carve((size_t)NH * NMEM * BDIM);
  float*       bT      = (float*)      carve((size_t)NH * BDIM * DH * 4);
  float*       o2      = (float*)      carve((size_t)NTOK * OUTF * 4);
  const size_t fixed = off;
  const size_t per = ((size_t)BDIM * NMEM * 2 + 256)    // wt
                   + ((size_t)NTOK * NMEM * 2 + 256)    // simb/attn (aliased)
                   + ((size_t)BDIM * NTOK * 4 + 256);   // o1t
  int G = 16;
  while (G > 1 && fixed + (size_t)G * per > ws_size) G >>= 1;
  unsigned short* wt   = (unsigned short*)carve((size_t)G * BDIM * NMEM * 2);
  short*          simb = (short*)         carve((size_t)G * NTOK * NMEM * 2);
  float*          o1t  = (float*)         carve((size_t)G * BDIM * NTOK * 4);
  const int gshift = __builtin_ctz(G);

  k_qgemm<<<dim3(16, 16), 256, 0, stream>>>(x, Wq, bq, q);
  k_code <<<dim3(64, 16), 256, 0, stream>>>(q, bp, code_i8);
  k_packw<<<dim3(NH * NMEM / 4), 256, 0, stream>>>(wm, wpk, w_i8);
  k_binT <<<dim3(8, 16), 256, 0, stream>>>(binv, bT);
  for (int h0 = 0; h0 < NH; h0 += G) {
    k_wt    <<<dim3(32, 8, G), 256, 0, stream>>>(wpk, wt, h0);
    k_sim   <<<dim3(64 * G),   256, 0, stream>>>(code_i8, w_i8, simb, h0, G - 1, gshift);
    k_stageF<<<dim3(32 * G),   512, 0, stream>>>((const unsigned short*)simb, wt, o1t, G - 1, gshift);
    k_proj  <<<dim3(16, G),    256, 0, stream>>>(o1t, bT, o2, h0);
  }
  k_ln<<<dim3(NTOK), 256, 0, stream>>>(o2, lnw, lnb, outp);
}

// Round 10
// 783.832 us; speedup vs baseline: 1.3028x; 1.3028x over previous
//
#include <hip/hip_runtime.h>
#include <hip/hip_fp16.h>

#define NTOK 1024
#define INF  1024
#define NH   16
#define DH   64
#define BDIM 512
#define NMEM 8192
#define OUTF 1024
#define NWRD 16   // 512 bits = 16 u32

typedef _Float16 f16x8 __attribute__((ext_vector_type(8)));
typedef float    f32x4 __attribute__((ext_vector_type(4)));
typedef int      i32x4 __attribute__((ext_vector_type(4)));

#define GLOAD16(G, L) __builtin_amdgcn_global_load_lds( \
    (const __attribute__((address_space(1))) unsigned int*)(G), \
    (__attribute__((address_space(3))) unsigned int*)(L), 16, 0, 0)

// score/TEMP * log2(e):  cos(pi/2*(1-s/512)) == sin(pi/2 * s/512), s = count
__device__ inline float score2(float s) {
  return 144.2695040889f * __sinf(s * 0.0030679615757712823f);
}

// ---------------- K1: q = x @ Wq^T + bq (f32, 64x64 tile) ----------------
__global__ __launch_bounds__(256) void k_qgemm(const float* __restrict__ x,
    const float* __restrict__ Wq, const float* __restrict__ bq, float* __restrict__ q) {
  __shared__ float As[64][17];
  __shared__ float Bs[64][17];
  const int tx = threadIdx.x & 15, ty = threadIdx.x >> 4;
  const int n0 = blockIdx.y * 64, o0 = blockIdx.x * 64;
  const int r = threadIdx.x >> 2, c4 = (threadIdx.x & 3) * 4;
  float acc[4][4] = {};
  for (int k0 = 0; k0 < INF; k0 += 16) {
    float4 av = *(const float4*)&x[(size_t)(n0 + r) * INF + k0 + c4];
    float4 bv = *(const float4*)&Wq[(size_t)(o0 + r) * INF + k0 + c4];
    __syncthreads();               // prev compute done before LDS overwrite
    As[r][c4+0] = av.x; As[r][c4+1] = av.y; As[r][c4+2] = av.z; As[r][c4+3] = av.w;
    Bs[r][c4+0] = bv.x; Bs[r][c4+1] = bv.y; Bs[r][c4+2] = bv.z; Bs[r][c4+3] = bv.w;
    __syncthreads();
    #pragma unroll
    for (int kk = 0; kk < 16; ++kk) {
      float a[4], b[4];
      #pragma unroll
      for (int i = 0; i < 4; ++i) a[i] = As[ty*4+i][kk];
      #pragma unroll
      for (int j = 0; j < 4; ++j) b[j] = Bs[tx*4+j][kk];
      #pragma unroll
      for (int i = 0; i < 4; ++i)
        #pragma unroll
        for (int j = 0; j < 4; ++j) acc[i][j] += a[i] * b[j];
    }
  }
  #pragma unroll
  for (int i = 0; i < 4; ++i) {
    const int row = n0 + ty*4 + i;
    #pragma unroll
    for (int j = 0; j < 4; ++j) {
      const int col = o0 + tx*4 + j;
      q[(size_t)row * OUTF + col] = acc[i][j] + bq[col];
    }
  }
}

// ---------------- K2: code_i8 = sign(q . bin_proj) as +-1 i8 ---------------
// norm of q doesn't change sign -> skip normalization entirely
__global__ __launch_bounds__(256) void k_code(const float* __restrict__ q,
    const float* __restrict__ bp, signed char* __restrict__ code_i8) {
  const int h = blockIdx.y, n0 = blockIdx.x * 16;
  __shared__ float ql[16][68];
  const int t = threadIdx.x;
  {
    const int r = t >> 4, c = (t & 15) * 4;
    float4 v = *(const float4*)&q[(size_t)(n0 + r) * OUTF + h * 64 + c];
    ql[r][c] = v.x; ql[r][c+1] = v.y; ql[r][c+2] = v.z; ql[r][c+3] = v.w;
  }
  __syncthreads();
  #pragma unroll
  for (int bb = 0; bb < 512; bb += 256) {
    const int b = bb + t;
    float bpv[64];
    const float4* src = (const float4*)&bp[((size_t)h * BDIM + b) * 64];
    #pragma unroll
    for (int j = 0; j < 16; ++j) {
      float4 v = src[j];
      bpv[j*4] = v.x; bpv[j*4+1] = v.y; bpv[j*4+2] = v.z; bpv[j*4+3] = v.w;
    }
    for (int n = 0; n < 16; ++n) {
      float dot = 0.f;
      #pragma unroll
      for (int d = 0; d < 64; ++d) dot += bpv[d] * ql[n][d];
      code_i8[((size_t)h * NTOK + n0 + n) * BDIM + b] = dot > 0.f ? 1 : -1;
    }
  }
}

// -------- K3: weight_matrix -> sign bits (for k_wt) AND +-1 i8 -------------
// w_i8 is written CHUNK-SWIZZLED: 16B chunk c of row m lands at physical
// chunk p=(c&~7)|((c&7)^(m&7)) so k_sim's linear global_load_lds staging +
// swizzled ds_read_b128 is bank-conflict-free (rule: swizzle both sides).
__global__ __launch_bounds__(256) void k_packw(const float* __restrict__ w,
    unsigned* __restrict__ wp, signed char* __restrict__ w_i8) {
  const int row  = blockIdx.x * 4 + (threadIdx.x >> 6);
  const int lane = threadIdx.x & 63;
  const float* src = w + (size_t)row * BDIM;
  unsigned my = 0;
  #pragma unroll
  for (int kk = 0; kk < 8; ++kk) {
    float v = src[kk * 64 + lane];
    const int c = kk * 4 + (lane >> 4);
    const int p = (c & ~7) | ((c & 7) ^ (row & 7));
    w_i8[(size_t)row * BDIM + p * 16 + (lane & 15)] = v > 0.f ? 1 : -1;
    unsigned long long m = __ballot(v > 0.f);
    if ((lane >> 1) == kk) my = (lane & 1) ? (unsigned)(m >> 32) : (unsigned)m;
  }
  if (lane < 16) wp[(size_t)row * NWRD + lane] = my;
}

// ---------------- K3b: transpose bin_inv [h][d][b] -> binT [h][b][d] -------
__global__ __launch_bounds__(256) void k_binT(const float* __restrict__ binv,
                                              float* __restrict__ bT) {
  const int h = blockIdx.y, b0 = blockIdx.x * 64;
  __shared__ float tl[64][65];
  const int t = threadIdx.x;
  #pragma unroll
  for (int i = 0; i < 4; ++i) {
    int fi = t + 256 * i;
    int d = fi >> 4, b = (fi & 15) * 4;
    float4 v = *(const float4*)&binv[((size_t)h * DH + d) * BDIM + b0 + b];
    tl[d][b] = v.x; tl[d][b+1] = v.y; tl[d][b+2] = v.z; tl[d][b+3] = v.w;
  }
  __syncthreads();
  #pragma unroll
  for (int i = 0; i < 4; ++i) {
    int fo = t + 256 * i;
    int bb = fo >> 4, dd = (fo & 15) * 4;
    float4 v = { tl[dd][bb], tl[dd+1][bb], tl[dd+2][bb], tl[dd+3][bb] };
    *(float4*)&bT[((size_t)h * BDIM + b0 + bb) * DH + dd] = v;
  }
}

// ------- K4: expand bits -> f16 wt [hg][b][m] (+-1), PRE-SWIZZLED ----------
// Within each 128B (64-m) window, 16B chunk g stores logical chunk g^(b&7),
// so stageF's linear global_load_lds + swizzled ds_read are conflict-free.
__global__ __launch_bounds__(256) void k_wt(const unsigned* __restrict__ wp,
    unsigned short* __restrict__ wt, int h0) {
  const int hg = blockIdx.z, h = h0 + hg;
  const int b0 = blockIdx.y * 64, m0 = blockIdx.x * 256;
  __shared__ unsigned bits[256][2];
  const int t = threadIdx.x;
  const unsigned* src = wp + (size_t)(h * NMEM + m0 + t) * NWRD + (b0 >> 5);
  bits[t][0] = src[0]; bits[t][1] = src[1];
  __syncthreads();
  const int b = t >> 2, ms = (t & 3) * 64;
  const int wd = b >> 5, sh = b & 31;
  const int bx7 = b & 7;
  unsigned short* dst = wt + ((size_t)hg * BDIM + b0 + b) * NMEM + m0 + ms;
  #pragma unroll
  for (int g = 0; g < 8; ++g) {
    const int pg = g ^ bx7;
    const int j = ms + g * 8;
    ushort4 v0, v1;
    v0.x = ((bits[j+0][wd] >> sh) & 1) ? 0x3C00 : 0xBC00;
    v0.y = ((bits[j+1][wd] >> sh) & 1) ? 0x3C00 : 0xBC00;
    v0.z = ((bits[j+2][wd] >> sh) & 1) ? 0x3C00 : 0xBC00;
    v0.w = ((bits[j+3][wd] >> sh) & 1) ? 0x3C00 : 0xBC00;
    v1.x = ((bits[j+4][wd] >> sh) & 1) ? 0x3C00 : 0xBC00;
    v1.y = ((bits[j+5][wd] >> sh) & 1) ? 0x3C00 : 0xBC00;
    v1.z = ((bits[j+6][wd] >> sh) & 1) ? 0x3C00 : 0xBC00;
    v1.w = ((bits[j+7][wd] >> sh) & 1) ? 0x3C00 : 0xBC00;
    *(ushort4*)&dst[pg * 8]     = v0;
    *(ushort4*)&dst[pg * 8 + 4] = v1;
  }
}

// ------- K5: sim = code @ w^T, i8 MFMA, async-staged B (m97 2-barrier) -----
// Block: one head, 64 rows, all 8192 m; 8 waves = 2 rowgroups x 4 memgroups.
// A codes persistent in VGPRs (64 regs); B tile (64 m x 512B = 32KB) staged
// SINGLE-buffered via global_load_lds with the proven stageF pattern:
// barrier -> 4x GLOAD16 -> barrier (drains vmcnt) -> ds_read+MFMA.
// w_i8 pre-chunk-swizzled in global -> linear DMA + swizzled read = no bank
// conflicts. Rowmax wave-local + one atomicMax. Tail: in-place exp -> attn
// f16 pre-swizzled for stageF (softmax 1/Z cancels in later normalize).
__global__ __launch_bounds__(512, 2) void k_sim(const signed char* __restrict__ code_i8,
    const signed char* __restrict__ w_i8, short* __restrict__ simb,
    int h0, int gmask, int gshift) {
  const int bid = (int)blockIdx.x;
  const int hg = bid & gmask, h = h0 + hg;      // XCD = bid%8 = h%8
  const int n0 = (bid >> gshift) * 64;
  const int t = threadIdx.x, lane = t & 63, wid = t >> 6;
  __shared__ __align__(16) signed char Bls[64 * 512];   // 32KB B tile
  __shared__ float sct[513];
  __shared__ int smaxl[64];
  if (t < 64) smaxl[t] = -(1 << 30);
  for (int p = t; p < 513; p += 512)
    sct[p] = score2(2.f * (float)p - 512.f);
  const int rg = wid >> 2, mg = wid & 3;
  // A frags: row = n0 + rg*32 + fi*16 + (lane&15), k = kk*64 + (lane>>4)*16
  i32x4 afrag[2][8];
  #pragma unroll
  for (int fi = 0; fi < 2; ++fi)
    #pragma unroll
    for (int kk = 0; kk < 8; ++kk)
      afrag[fi][kk] = *(const i32x4*)(code_i8 +
          ((size_t)h * NTOK + n0 + rg * 32 + fi * 16 + (lane & 15)) * BDIM +
          kk * 64 + (lane >> 4) * 16);
  const signed char* wb = w_i8 + (size_t)h * NMEM * BDIM + (size_t)t * 16;
  signed char* const d0 = &Bls[wid * 1024];     // wave-uniform LDS base
  int vmax[2][4];
  #pragma unroll
  for (int fi = 0; fi < 2; ++fi)
    #pragma unroll
    for (int j = 0; j < 4; ++j) vmax[fi][j] = -(1 << 30);
  short* srow = simb + ((size_t)hg * NTOK + n0) * NMEM;
  for (int tile = 0; tile < 128; ++tile) {
    const signed char* s = wb + (size_t)tile * 64 * BDIM;
    __syncthreads();                  // previous tile fully consumed
    GLOAD16(s, d0); GLOAD16(s + 8192, d0 + 8192);
    GLOAD16(s + 16384, d0 + 16384); GLOAD16(s + 24576, d0 + 24576);
    __syncthreads();                  // drains vmcnt -> tile ready
    const signed char* bls = &Bls[(mg * 16 + (lane & 15)) * 512];
    i32x4 acc0 = {}, acc1 = {};
    #pragma unroll
    for (int kk = 0; kk < 8; ++kk) {
      const int c = kk * 4 + (lane >> 4);
      const int p = (c & ~7) | ((c & 7) ^ (lane & 7));
      i32x4 b = *(const i32x4*)(bls + p * 16);
      acc0 = __builtin_amdgcn_mfma_i32_16x16x64_i8(afrag[0][kk], b, acc0, 0, 0, 0);
      acc1 = __builtin_amdgcn_mfma_i32_16x16x64_i8(afrag[1][kk], b, acc1, 0, 0, 0);
    }
    const int m0 = tile * 64 + mg * 16 + (lane & 15);
    #pragma unroll
    for (int j = 0; j < 4; ++j) {
      const int r0 = rg * 32 + (lane >> 4) * 4 + j;         // C: row=(l>>4)*4+reg
      srow[(size_t)r0 * NMEM + m0]        = (short)acc0[j]; // C: col=l&15
      srow[(size_t)(r0 + 16) * NMEM + m0] = (short)acc1[j];
      vmax[0][j] = max(vmax[0][j], acc0[j]);
      vmax[1][j] = max(vmax[1][j], acc1[j]);
    }
  }
  #pragma unroll
  for (int fi = 0; fi < 2; ++fi)
    #pragma unroll
    for (int j = 0; j < 4; ++j) {
      int v = vmax[fi][j];
      #pragma unroll
      for (int s = 1; s < 16; s <<= 1) v = max(v, __shfl_xor(v, s));
      if ((lane & 15) == 0)
        atomicMax(&smaxl[rg * 32 + fi * 16 + (lane >> 4) * 4 + j], v);
    }
  __syncthreads();   // smaxl final, all sim stores done (wg-scope visibility)
  unsigned short* arow = (unsigned short*)srow;
  for (int it = 0; it < 16; ++it) {
    const int gw = it * 512 + t;               // window id in [0, 8192)
    const int row = gw >> 7, win = gw & 127;   // 128 x 64-elem windows per row
    const float sm2 = sct[(smaxl[row] + 512) >> 1];
    const short* sp = srow + (size_t)row * NMEM + win * 64;
    uint4 sv[8];
    #pragma unroll
    for (int c = 0; c < 8; ++c) sv[c] = *(const uint4*)(sp + c * 8);
    const int rx = row & 7;                    // n0%64==0 -> local row&7 ok
    unsigned short* dp = arow + (size_t)row * NMEM + win * 64;
    #pragma unroll
    for (int c = 0; c < 8; ++c) {
      unsigned ov[4];
      #pragma unroll
      for (int k = 0; k < 4; ++k) {
        const unsigned w2 = (&sv[c].x)[k];
        const int lo = (int)(short)(w2 & 0xffffu);
        const int hi = (int)(short)(w2 >> 16);
        float p0 = exp2f(sct[(lo + 512) >> 1] - sm2);
        float p1 = exp2f(sct[(hi + 512) >> 1] - sm2);
        ov[k] = (unsigned)__half_as_ushort(__float2half(p0))
              | ((unsigned)__half_as_ushort(__float2half(p1)) << 16);
      }
      *(uint4*)(dp + (c ^ rx) * 8) = make_uint4(ov[0], ov[1], ov[2], ov[3]);
    }
  }
}

// ------- K6: o1^T = (attn @ wt)^T, pure f16 MFMA GEMM, 128x128 tile --------
// Both operands pre-swizzled in global; linear global_load_lds staging;
// XOR-deswizzled ds_read_b128 (conflict-free, verified R5: BANK_CONFLICT=0).
__global__ __launch_bounds__(512, 2) void k_stageF(const unsigned short* __restrict__ attn,
    const unsigned short* __restrict__ wt, float* __restrict__ o1t,
    int gmask, int gshift) {
  __shared__ __align__(16) _Float16 Al[128][64];
  __shared__ __align__(16) _Float16 Bl[128][64];
  const int wg = (int)blockIdx.x;
  const int hg = wg & gmask;                   // XCD = wg%8 = hg%8
  const int rest = wg >> gshift;
  const int nt = rest & 7, bt = rest >> 3;
  const int n0 = nt * 128, b0 = bt * 128;
  const int t = threadIdx.x;
  const int lane = t & 63, wid = t >> 6;
  const int wm = wid >> 2, wn = wid & 3;
  f32x4 acc[4][2];
  #pragma unroll
  for (int i = 0; i < 4; ++i)
    #pragma unroll
    for (int j = 0; j < 2; ++j) acc[i][j] = (f32x4){0.f, 0.f, 0.f, 0.f};

  const unsigned short* ag = attn + ((size_t)hg * NTOK + n0 + 16*wid + (lane >> 3)) * NMEM + (lane & 7) * 8;
  const unsigned short* bg = wt   + ((size_t)hg * BDIM + b0 + 16*wid + (lane >> 3)) * NMEM + (lane & 7) * 8;
  _Float16* al0 = &Al[16 * wid][0];            // wave-uniform LDS bases
  _Float16* bl0 = &Bl[16 * wid][0];

  for (int k0 = 0; k0 < NMEM; k0 += 64) {
    __syncthreads();                    // previous tile fully consumed
    GLOAD16(ag + k0,            al0);
    GLOAD16(ag + k0 + 8 * NMEM, al0 + 8 * 64);
    GLOAD16(bg + k0,            bl0);
    GLOAD16(bg + k0 + 8 * NMEM, bl0 + 8 * 64);
    __syncthreads();                    // drains vmcnt -> tile ready
    #pragma unroll
    for (int kk = 0; kk < 64; kk += 32) {
      const int phys = (((kk >> 3) + (lane >> 4)) ^ (lane & 7)) * 8;
      f16x8 af[4], bf[2];
      #pragma unroll
      for (int fm = 0; fm < 4; ++fm)
        af[fm] = *(const f16x8*)&Al[wm*64 + fm*16 + (lane & 15)][phys];
      #pragma unroll
      for (int fn = 0; fn < 2; ++fn)
        bf[fn] = *(const f16x8*)&Bl[wn*32 + fn*16 + (lane & 15)][phys];
      #pragma unroll
      for (int fm = 0; fm < 4; ++fm)
        #pragma unroll
        for (int fn = 0; fn < 2; ++fn)
          acc[fm][fn] = __builtin_amdgcn_mfma_f32_16x16x32_f16(af[fm], bf[fn], acc[fm][fn], 0, 0, 0);
    }
  }
  #pragma unroll
  for (int fm = 0; fm < 4; ++fm) {
    const int rowb = n0 + wm*64 + fm*16 + (lane >> 4) * 4;   // C: row=(l>>4)*4+reg
    #pragma unroll
    for (int fn = 0; fn < 2; ++fn) {
      const int col = b0 + wn*32 + fn*16 + (lane & 15);      // C: col=l&15
      *(f32x4*)&o1t[((size_t)hg * BDIM + col) * NTOK + rowb] = acc[fm][fn];
    }
  }
}

// ------- K7: out[n][h*64+d] = normalize_d( o1 . bin_inv ) ------------------
__global__ __launch_bounds__(256) void k_proj(const float* __restrict__ o1t,
    const float* __restrict__ bT, float* __restrict__ o2, int h0) {
  const int hg = blockIdx.y, h = h0 + hg;
  const int n0 = blockIdx.x * 64;
  __shared__ float bl[128][68];
  __shared__ float ol[128][68];
  __shared__ float outl[64][68];
  __shared__ float nrm[64];
  const int t = threadIdx.x;
  const int tx = t & 15, ty = t >> 4;
  float acc[4][4] = {};
  for (int c = 0; c < 4; ++c) {
    const int bb0 = c * 128;
    __syncthreads();
    #pragma unroll
    for (int i = 0; i < 8; ++i) {
      int fi = t + 256 * i;
      int rr = fi >> 4, cc = (fi & 15) * 4;
      *(float4*)&bl[rr][cc] = *(const float4*)&bT[((size_t)h * BDIM + bb0 + rr) * DH + cc];
      *(float4*)&ol[rr][cc] = *(const float4*)&o1t[((size_t)hg * BDIM + bb0 + rr) * NTOK + n0 + cc];
    }
    __syncthreads();
    for (int bb = 0; bb < 128; ++bb) {
      float4 bd = *(const float4*)&bl[bb][tx * 4];
      float4 on = *(const float4*)&ol[bb][ty * 4];
      float ai[4] = {on.x, on.y, on.z, on.w};
      float bj[4] = {bd.x, bd.y, bd.z, bd.w};
      #pragma unroll
      for (int i = 0; i < 4; ++i)
        #pragma unroll
        for (int j = 0; j < 4; ++j) acc[i][j] += ai[i] * bj[j];
    }
  }
  __syncthreads();
  #pragma unroll
  for (int i = 0; i < 4; ++i)
    #pragma unroll
    for (int j = 0; j < 4; ++j) outl[ty*4 + i][tx*4 + j] = acc[i][j];
  __syncthreads();
  if (t < 64) {
    float s = 0.f;
    #pragma unroll
    for (int d = 0; d < 64; ++d) { float v = outl[t][d]; s += v * v; }
    nrm[t] = 1.f / sqrtf(s);
  }
  __syncthreads();
  {
    const int n = t >> 2, dg = (t & 3) * 16;
    #pragma unroll
    for (int j = 0; j < 16; ++j)
      o2[(size_t)(n0 + n) * OUTF + h * 64 + dg + j] = outl[n][dg + j] * nrm[n];
  }
}

// ------- K8: LayerNorm over 1024 features ----------------------------------
__global__ __launch_bounds__(256) void k_ln(const float* __restrict__ o2,
    const float* __restrict__ lnw, const float* __restrict__ lnb, float* __restrict__ out) {
  const int n = blockIdx.x, t = threadIdx.x;
  __shared__ float red[4];
  float4 v = *(const float4*)&o2[(size_t)n * OUTF + t * 4];
  float s = v.x + v.y + v.z + v.w;
  const int lane = t & 63, wid = t >> 6;
  #pragma unroll
  for (int off = 32; off; off >>= 1) s += __shfl_down(s, off);
  if (lane == 0) red[wid] = s;
  __syncthreads();
  const float mu = (red[0] + red[1] + red[2] + red[3]) * (1.f / 1024.f);
  float4 d = {v.x - mu, v.y - mu, v.z - mu, v.w - mu};
  float s2 = d.x*d.x + d.y*d.y + d.z*d.z + d.w*d.w;
  #pragma unroll
  for (int off = 32; off; off >>= 1) s2 += __shfl_down(s2, off);
  __syncthreads();
  if (lane == 0) red[wid] = s2;
  __syncthreads();
  const float var = (red[0] + red[1] + red[2] + red[3]) * (1.f / 1024.f);
  const float inv = 1.f / sqrtf(var + 1e-5f);
  float4 w = *(const float4*)&lnw[t * 4];
  float4 b = *(const float4*)&lnb[t * 4];
  float4 o = { d.x*inv*w.x + b.x, d.y*inv*w.y + b.y,
               d.z*inv*w.z + b.z, d.w*inv*w.w + b.w };
  *(float4*)&out[(size_t)n * OUTF + t * 4] = o;
}

extern "C" void kernel_launch(void* const* d_in, const int* in_sizes, int n_in,
                              void* d_out, int out_size, void* d_ws, size_t ws_size,
                              hipStream_t stream) {
  (void)in_sizes; (void)n_in; (void)out_size;
  const float* x    = (const float*)d_in[0];
  const float* Wq   = (const float*)d_in[1];
  const float* bq   = (const float*)d_in[2];
  const float* bp   = (const float*)d_in[3];
  const float* binv = (const float*)d_in[4];
  const float* wm   = (const float*)d_in[5];
  const float* lnw  = (const float*)d_in[6];
  const float* lnb  = (const float*)d_in[7];
  float* outp = (float*)d_out;

  char* ws = (char*)d_ws;
  size_t off = 0;
  auto carve = [&](size_t bytes) -> char* {
    char* p = ws + off;
    off += (bytes + 255) & ~(size_t)255;
    return p;
  };
  float*       q       = (float*)      carve((size_t)NTOK * OUTF * 4);
  signed char* code_i8 = (signed char*)carve((size_t)NH * NTOK * BDIM);
  unsigned*    wpk     = (unsigned*)   carve((size_t)NH * NMEM * NWRD * 4);
  signed char* w_i8    = (signed char*)carve((size_t)NH * NMEM * BDIM);
  float*       bT      = (float*)      carve((size_t)NH * BDIM * DH * 4);
  float*       o2      = (float*)      carve((size_t)NTOK * OUTF * 4);
  const size_t fixed = off;
  const size_t per = ((size_t)BDIM * NMEM * 2 + 256)    // wt
                   + ((size_t)NTOK * NMEM * 2 + 256)    // simb/attn (aliased)
                   + ((size_t)BDIM * NTOK * 4 + 256);   // o1t
  int G = 16;
  while (G > 1 && fixed + (size_t)G * per > ws_size) G >>= 1;
  unsigned short* wt   = (unsigned short*)carve((size_t)G * BDIM * NMEM * 2);
  short*          simb = (short*)         carve((size_t)G * NTOK * NMEM * 2);
  float*          o1t  = (float*)         carve((size_t)G * BDIM * NTOK * 4);
  const int gshift = __builtin_ctz(G);

  k_qgemm<<<dim3(16, 16), 256, 0, stream>>>(x, Wq, bq, q);
  k_code <<<dim3(64, 16), 256, 0, stream>>>(q, bp, code_i8);
  k_packw<<<dim3(NH * NMEM / 4), 256, 0, stream>>>(wm, wpk, w_i8);
  k_binT <<<dim3(8, 16), 256, 0, stream>>>(binv, bT);
  for (int h0 = 0; h0 < NH; h0 += G) {
    k_wt    <<<dim3(32, 8, G), 256, 0, stream>>>(wpk, wt, h0);
    k_sim   <<<dim3(16 * G),   512, 0, stream>>>(code_i8, w_i8, simb, h0, G - 1, gshift);
    k_stageF<<<dim3(32 * G),   512, 0, stream>>>((const unsigned short*)simb, wt, o1t, G - 1, gshift);
    k_proj  <<<dim3(16, G),    256, 0, stream>>>(o1t, bT, o2, h0);
  }
  k_ln<<<dim3(NTOK), 256, 0, stream>>>(o2, lnw, lnb, outp);
}

// Round 12
// 758.789 us; speedup vs baseline: 1.3458x; 1.0330x over previous
//
#include <hip/hip_runtime.h>
#include <hip/hip_fp16.h>

#define NTOK 1024
#define INF  1024
#define NH   16
#define DH   64
#define BDIM 512
#define NMEM 8192
#define OUTF 1024
#define NWRD 16   // 512 bits = 16 u32

typedef _Float16 f16x8 __attribute__((ext_vector_type(8)));
typedef float    f32x4 __attribute__((ext_vector_type(4)));
typedef int      i32x4 __attribute__((ext_vector_type(4)));

#define GLOAD16(G, L) __builtin_amdgcn_global_load_lds( \
    (const __attribute__((address_space(1))) unsigned int*)(G), \
    (__attribute__((address_space(3))) unsigned int*)(L), 16, 0, 0)

// score/TEMP * log2(e):  cos(pi/2*(1-s/512)) == sin(pi/2 * s/512), s = count
__device__ inline float score2(float s) {
  return 144.2695040889f * __sinf(s * 0.0030679615757712823f);
}

// ---------------- K1: q = x @ Wq^T + bq (f32, 64x64 tile) ----------------
__global__ __launch_bounds__(256) void k_qgemm(const float* __restrict__ x,
    const float* __restrict__ Wq, const float* __restrict__ bq, float* __restrict__ q) {
  __shared__ float As[64][17];
  __shared__ float Bs[64][17];
  const int tx = threadIdx.x & 15, ty = threadIdx.x >> 4;
  const int n0 = blockIdx.y * 64, o0 = blockIdx.x * 64;
  const int r = threadIdx.x >> 2, c4 = (threadIdx.x & 3) * 4;
  float acc[4][4] = {};
  for (int k0 = 0; k0 < INF; k0 += 16) {
    float4 av = *(const float4*)&x[(size_t)(n0 + r) * INF + k0 + c4];
    float4 bv = *(const float4*)&Wq[(size_t)(o0 + r) * INF + k0 + c4];
    __syncthreads();               // prev compute done before LDS overwrite
    As[r][c4+0] = av.x; As[r][c4+1] = av.y; As[r][c4+2] = av.z; As[r][c4+3] = av.w;
    Bs[r][c4+0] = bv.x; Bs[r][c4+1] = bv.y; Bs[r][c4+2] = bv.z; Bs[r][c4+3] = bv.w;
    __syncthreads();
    #pragma unroll
    for (int kk = 0; kk < 16; ++kk) {
      float a[4], b[4];
      #pragma unroll
      for (int i = 0; i < 4; ++i) a[i] = As[ty*4+i][kk];
      #pragma unroll
      for (int j = 0; j < 4; ++j) b[j] = Bs[tx*4+j][kk];
      #pragma unroll
      for (int i = 0; i < 4; ++i)
        #pragma unroll
        for (int j = 0; j < 4; ++j) acc[i][j] += a[i] * b[j];
    }
  }
  #pragma unroll
  for (int i = 0; i < 4; ++i) {
    const int row = n0 + ty*4 + i;
    #pragma unroll
    for (int j = 0; j < 4; ++j) {
      const int col = o0 + tx*4 + j;
      q[(size_t)row * OUTF + col] = acc[i][j] + bq[col];
    }
  }
}

// ---------------- K2: code_i8 = sign(q . bin_proj) as +-1 i8 ---------------
// norm of q doesn't change sign -> skip normalization entirely
__global__ __launch_bounds__(256) void k_code(const float* __restrict__ q,
    const float* __restrict__ bp, signed char* __restrict__ code_i8) {
  const int h = blockIdx.y, n0 = blockIdx.x * 16;
  __shared__ float ql[16][68];
  const int t = threadIdx.x;
  {
    const int r = t >> 4, c = (t & 15) * 4;
    float4 v = *(const float4*)&q[(size_t)(n0 + r) * OUTF + h * 64 + c];
    ql[r][c] = v.x; ql[r][c+1] = v.y; ql[r][c+2] = v.z; ql[r][c+3] = v.w;
  }
  __syncthreads();
  #pragma unroll
  for (int bb = 0; bb < 512; bb += 256) {
    const int b = bb + t;
    float bpv[64];
    const float4* src = (const float4*)&bp[((size_t)h * BDIM + b) * 64];
    #pragma unroll
    for (int j = 0; j < 16; ++j) {
      float4 v = src[j];
      bpv[j*4] = v.x; bpv[j*4+1] = v.y; bpv[j*4+2] = v.z; bpv[j*4+3] = v.w;
    }
    for (int n = 0; n < 16; ++n) {
      float dot = 0.f;
      #pragma unroll
      for (int d = 0; d < 64; ++d) dot += bpv[d] * ql[n][d];
      code_i8[((size_t)h * NTOK + n0 + n) * BDIM + b] = dot > 0.f ? 1 : -1;
    }
  }
}

// -------- K3: weight_matrix -> sign bits (for k_wt) AND +-1 i8 -------------
// w_i8 is written CHUNK-SWIZZLED: 16B chunk c of row m lands at physical
// chunk p=(c&~7)|((c&7)^(m&7)) so k_sim's linear global_load_lds staging +
// swizzled ds_read_b128 is bank-conflict-free (rule: swizzle both sides).
__global__ __launch_bounds__(256) void k_packw(const float* __restrict__ w,
    unsigned* __restrict__ wp, signed char* __restrict__ w_i8) {
  const int row  = blockIdx.x * 4 + (threadIdx.x >> 6);
  const int lane = threadIdx.x & 63;
  const float* src = w + (size_t)row * BDIM;
  unsigned my = 0;
  #pragma unroll
  for (int kk = 0; kk < 8; ++kk) {
    float v = src[kk * 64 + lane];
    const int c = kk * 4 + (lane >> 4);
    const int p = (c & ~7) | ((c & 7) ^ (row & 7));
    w_i8[(size_t)row * BDIM + p * 16 + (lane & 15)] = v > 0.f ? 1 : -1;
    unsigned long long m = __ballot(v > 0.f);
    if ((lane >> 1) == kk) my = (lane & 1) ? (unsigned)(m >> 32) : (unsigned)m;
  }
  if (lane < 16) wp[(size_t)row * NWRD + lane] = my;
}

// ---------------- K3b: transpose bin_inv [h][d][b] -> binT [h][b][d] -------
__global__ __launch_bounds__(256) void k_binT(const float* __restrict__ binv,
                                              float* __restrict__ bT) {
  const int h = blockIdx.y, b0 = blockIdx.x * 64;
  __shared__ float tl[64][65];
  const int t = threadIdx.x;
  #pragma unroll
  for (int i = 0; i < 4; ++i) {
    int fi = t + 256 * i;
    int d = fi >> 4, b = (fi & 15) * 4;
    float4 v = *(const float4*)&binv[((size_t)h * DH + d) * BDIM + b0 + b];
    tl[d][b] = v.x; tl[d][b+1] = v.y; tl[d][b+2] = v.z; tl[d][b+3] = v.w;
  }
  __syncthreads();
  #pragma unroll
  for (int i = 0; i < 4; ++i) {
    int fo = t + 256 * i;
    int bb = fo >> 4, dd = (fo & 15) * 4;
    float4 v = { tl[dd][bb], tl[dd+1][bb], tl[dd+2][bb], tl[dd+3][bb] };
    *(float4*)&bT[((size_t)h * BDIM + b0 + bb) * DH + dd] = v;
  }
}

// ------- K4: expand bits -> f16 wt [hg][b][m] (+-1), PRE-SWIZZLED ----------
// Within each 128B (64-m) window, 16B chunk g stores logical chunk g^(b&7),
// so stageF's linear global_load_lds + swizzled ds_read are conflict-free.
__global__ __launch_bounds__(256) void k_wt(const unsigned* __restrict__ wp,
    unsigned short* __restrict__ wt, int h0) {
  const int hg = blockIdx.z, h = h0 + hg;
  const int b0 = blockIdx.y * 64, m0 = blockIdx.x * 256;
  __shared__ unsigned bits[256][2];
  const int t = threadIdx.x;
  const unsigned* src = wp + (size_t)(h * NMEM + m0 + t) * NWRD + (b0 >> 5);
  bits[t][0] = src[0]; bits[t][1] = src[1];
  __syncthreads();
  const int b = t >> 2, ms = (t & 3) * 64;
  const int wd = b >> 5, sh = b & 31;
  const int bx7 = b & 7;
  unsigned short* dst = wt + ((size_t)hg * BDIM + b0 + b) * NMEM + m0 + ms;
  #pragma unroll
  for (int g = 0; g < 8; ++g) {
    const int pg = g ^ bx7;
    const int j = ms + g * 8;
    ushort4 v0, v1;
    v0.x = ((bits[j+0][wd] >> sh) & 1) ? 0x3C00 : 0xBC00;
    v0.y = ((bits[j+1][wd] >> sh) & 1) ? 0x3C00 : 0xBC00;
    v0.z = ((bits[j+2][wd] >> sh) & 1) ? 0x3C00 : 0xBC00;
    v0.w = ((bits[j+3][wd] >> sh) & 1) ? 0x3C00 : 0xBC00;
    v1.x = ((bits[j+4][wd] >> sh) & 1) ? 0x3C00 : 0xBC00;
    v1.y = ((bits[j+5][wd] >> sh) & 1) ? 0x3C00 : 0xBC00;
    v1.z = ((bits[j+6][wd] >> sh) & 1) ? 0x3C00 : 0xBC00;
    v1.w = ((bits[j+7][wd] >> sh) & 1) ? 0x3C00 : 0xBC00;
    *(ushort4*)&dst[pg * 8]     = v0;
    *(ushort4*)&dst[pg * 8 + 4] = v1;
  }
}

// ------- K5: sim = code @ w^T, i8 MFMA, single-buffered async B staging ----
// OCCUPANCY restructure of the PROVEN R10 skeleton (2 barriers/tile, no
// stage-ahead — that schedule raced twice and is retired):
//   * 32 rows/block, grid 32*G = 512 -> 2 blocks/CU co-resident; one block's
//     barrier drain overlaps the other's compute (m114 implicit overlap).
//   * 128-mem tiles (64KB LDS) -> half the barrier round-trips.
// 8 waves = 2 rowgroups(16) x 4 memgroups(32 m each). A codes in VGPRs.
// w_i8 pre-chunk-swizzled in global -> linear DMA + swizzled read, no bank
// conflicts. Rowmax wave-local + one atomicMax. Tail: in-place exp -> attn
// f16 pre-swizzled for stageF (softmax 1/Z cancels in later normalize).
__global__ __launch_bounds__(512, 2) void k_sim(const signed char* __restrict__ code_i8,
    const signed char* __restrict__ w_i8, short* __restrict__ simb,
    int h0, int gmask, int gshift) {
  const int bid = (int)blockIdx.x;
  const int hg = bid & gmask, h = h0 + hg;      // XCD = bid%8 = h%8 (convoy)
  const int n0 = (bid >> gshift) * 32;
  const int t = threadIdx.x, lane = t & 63, wid = t >> 6;
  __shared__ __align__(16) signed char Bls[128 * 512];   // 64KB B tile
  __shared__ float sct[513];
  __shared__ int smaxl[32];
  if (t < 32) smaxl[t] = -(1 << 30);
  for (int p = t; p < 513; p += 512)
    sct[p] = score2(2.f * (float)p - 512.f);
  const int rg = wid >> 2, mg = wid & 3;
  // A frags: row = n0 + rg*16 + (lane&15), k = kk*64 + (lane>>4)*16
  i32x4 afrag[8];
  #pragma unroll
  for (int kk = 0; kk < 8; ++kk)
    afrag[kk] = *(const i32x4*)(code_i8 +
        ((size_t)h * NTOK + n0 + rg * 16 + (lane & 15)) * BDIM +
        kk * 64 + (lane >> 4) * 16);
  const signed char* wb = w_i8 + (size_t)h * NMEM * BDIM + (size_t)t * 16;
  signed char* const d0 = &Bls[wid * 1024];     // wave-uniform LDS base
  int vmax[4] = {-(1 << 30), -(1 << 30), -(1 << 30), -(1 << 30)};
  short* srow = simb + ((size_t)hg * NTOK + n0) * NMEM;
  for (int tile = 0; tile < 64; ++tile) {       // 128 m per tile
    const signed char* s = wb + (size_t)tile * 128 * BDIM;
    __syncthreads();                  // previous tile fully consumed
    #pragma unroll
    for (int seg = 0; seg < 8; ++seg)
      GLOAD16(s + seg * 8192, d0 + seg * 8192);
    __syncthreads();                  // drains vmcnt -> tile ready
    #pragma unroll
    for (int msub = 0; msub < 2; ++msub) {
      const signed char* bls = &Bls[(mg * 32 + msub * 16 + (lane & 15)) * 512];
      i32x4 acc = {};
      #pragma unroll
      for (int kk = 0; kk < 8; ++kk) {
        const int c = kk * 4 + (lane >> 4);
        const int p = (c & ~7) | ((c & 7) ^ (lane & 7));
        i32x4 b = *(const i32x4*)(bls + p * 16);
        acc = __builtin_amdgcn_mfma_i32_16x16x64_i8(afrag[kk], b, acc, 0, 0, 0);
      }
      const int m0 = tile * 128 + mg * 32 + msub * 16 + (lane & 15);
      #pragma unroll
      for (int j = 0; j < 4; ++j) {
        const int r0 = rg * 16 + (lane >> 4) * 4 + j;       // C: row=(l>>4)*4+reg
        srow[(size_t)r0 * NMEM + m0] = (short)acc[j];       // C: col=l&15
        vmax[j] = max(vmax[j], acc[j]);
      }
    }
  }
  #pragma unroll
  for (int j = 0; j < 4; ++j) {
    int v = vmax[j];
    #pragma unroll
    for (int s = 1; s < 16; s <<= 1) v = max(v, __shfl_xor(v, s));
    if ((lane & 15) == 0)
      atomicMax(&smaxl[rg * 16 + (lane >> 4) * 4 + j], v);
  }
  __syncthreads();   // smaxl final, all sim stores done (wg-scope visibility)
  unsigned short* arow = (unsigned short*)srow;
  for (int it = 0; it < 8; ++it) {
    const int gw = it * 512 + t;               // window id in [0, 4096)
    const int row = gw >> 7, win = gw & 127;   // 128 x 64-elem windows per row
    const float sm2 = sct[(smaxl[row] + 512) >> 1];
    const short* sp = srow + (size_t)row * NMEM + win * 64;
    uint4 sv[8];
    #pragma unroll
    for (int c = 0; c < 8; ++c) sv[c] = *(const uint4*)(sp + c * 8);
    const int rx = row & 7;                    // n0%32==0 -> local row&7 ok
    unsigned short* dp = arow + (size_t)row * NMEM + win * 64;
    #pragma unroll
    for (int c = 0; c < 8; ++c) {
      unsigned ov[4];
      #pragma unroll
      for (int k = 0; k < 4; ++k) {
        const unsigned w2 = (&sv[c].x)[k];
        const int lo = (int)(short)(w2 & 0xffffu);
        const int hi = (int)(short)(w2 >> 16);
        float p0 = exp2f(sct[(lo + 512) >> 1] - sm2);
        float p1 = exp2f(sct[(hi + 512) >> 1] - sm2);
        ov[k] = (unsigned)__half_as_ushort(__float2half(p0))
              | ((unsigned)__half_as_ushort(__float2half(p1)) << 16);
      }
      *(uint4*)(dp + (c ^ rx) * 8) = make_uint4(ov[0], ov[1], ov[2], ov[3]);
    }
  }
}

// ------- K6: o1^T = (attn @ wt)^T, pure f16 MFMA GEMM, 128x128 tile --------
// Both operands pre-swizzled in global; linear global_load_lds staging;
// XOR-deswizzled ds_read_b128.
__global__ __launch_bounds__(512, 2) void k_stageF(const unsigned short* __restrict__ attn,
    const unsigned short* __restrict__ wt, float* __restrict__ o1t,
    int gmask, int gshift) {
  __shared__ __align__(16) _Float16 Al[128][64];
  __shared__ __align__(16) _Float16 Bl[128][64];
  const int wg = (int)blockIdx.x;
  const int hg = wg & gmask;                   // XCD = wg%8 = hg%8
  const int rest = wg >> gshift;
  const int nt = rest & 7, bt = rest >> 3;
  const int n0 = nt * 128, b0 = bt * 128;
  const int t = threadIdx.x;
  const int lane = t & 63, wid = t >> 6;
  const int wm = wid >> 2, wn = wid & 3;
  f32x4 acc[4][2];
  #pragma unroll
  for (int i = 0; i < 4; ++i)
    #pragma unroll
    for (int j = 0; j < 2; ++j) acc[i][j] = (f32x4){0.f, 0.f, 0.f, 0.f};

  const unsigned short* ag = attn + ((size_t)hg * NTOK + n0 + 16*wid + (lane >> 3)) * NMEM + (lane & 7) * 8;
  const unsigned short* bg = wt   + ((size_t)hg * BDIM + b0 + 16*wid + (lane >> 3)) * NMEM + (lane & 7) * 8;
  _Float16* al0 = &Al[16 * wid][0];            // wave-uniform LDS bases
  _Float16* bl0 = &Bl[16 * wid][0];

  for (int k0 = 0; k0 < NMEM; k0 += 64) {
    __syncthreads();                    // previous tile fully consumed
    GLOAD16(ag + k0,            al0);
    GLOAD16(ag + k0 + 8 * NMEM, al0 + 8 * 64);
    GLOAD16(bg + k0,            bl0);
    GLOAD16(bg + k0 + 8 * NMEM, bl0 + 8 * 64);
    __syncthreads();                    // drains vmcnt -> tile ready
    #pragma unroll
    for (int kk = 0; kk < 64; kk += 32) {
      const int phys = (((kk >> 3) + (lane >> 4)) ^ (lane & 7)) * 8;
      f16x8 af[4], bf[2];
      #pragma unroll
      for (int fm = 0; fm < 4; ++fm)
        af[fm] = *(const f16x8*)&Al[wm*64 + fm*16 + (lane & 15)][phys];
      #pragma unroll
      for (int fn = 0; fn < 2; ++fn)
        bf[fn] = *(const f16x8*)&Bl[wn*32 + fn*16 + (lane & 15)][phys];
      #pragma unroll
      for (int fm = 0; fm < 4; ++fm)
        #pragma unroll
        for (int fn = 0; fn < 2; ++fn)
          acc[fm][fn] = __builtin_amdgcn_mfma_f32_16x16x32_f16(af[fm], bf[fn], acc[fm][fn], 0, 0, 0);
    }
  }
  #pragma unroll
  for (int fm = 0; fm < 4; ++fm) {
    const int rowb = n0 + wm*64 + fm*16 + (lane >> 4) * 4;   // C: row=(l>>4)*4+reg
    #pragma unroll
    for (int fn = 0; fn < 2; ++fn) {
      const int col = b0 + wn*32 + fn*16 + (lane & 15);      // C: col=l&15
      *(f32x4*)&o1t[((size_t)hg * BDIM + col) * NTOK + rowb] = acc[fm][fn];
    }
  }
}

// ------- K7: out[n][h*64+d] = normalize_d( o1 . bin_inv ) ------------------
__global__ __launch_bounds__(256) void k_proj(const float* __restrict__ o1t,
    const float* __restrict__ bT, float* __restrict__ o2, int h0) {
  const int hg = blockIdx.y, h = h0 + hg;
  const int n0 = blockIdx.x * 64;
  __shared__ float bl[128][68];
  __shared__ float ol[128][68];
  __shared__ float outl[64][68];
  __shared__ float nrm[64];
  const int t = threadIdx.x;
  const int tx = t & 15, ty = t >> 4;
  float acc[4][4] = {};
  for (int c = 0; c < 4; ++c) {
    const int bb0 = c * 128;
    __syncthreads();
    #pragma unroll
    for (int i = 0; i < 8; ++i) {
      int fi = t + 256 * i;
      int rr = fi >> 4, cc = (fi & 15) * 4;
      *(float4*)&bl[rr][cc] = *(const float4*)&bT[((size_t)h * BDIM + bb0 + rr) * DH + cc];
      *(float4*)&ol[rr][cc] = *(const float4*)&o1t[((size_t)hg * BDIM + bb0 + rr) * NTOK + n0 + cc];
    }
    __syncthreads();
    for (int bb = 0; bb < 128; ++bb) {
      float4 bd = *(const float4*)&bl[bb][tx * 4];
      float4 on = *(const float4*)&ol[bb][ty * 4];
      float ai[4] = {on.x, on.y, on.z, on.w};
      float bj[4] = {bd.x, bd.y, bd.z, bd.w};
      #pragma unroll
      for (int i = 0; i < 4; ++i)
        #pragma unroll
        for (int j = 0; j < 4; ++j) acc[i][j] += ai[i] * bj[j];
    }
  }
  __syncthreads();
  #pragma unroll
  for (int i = 0; i < 4; ++i)
    #pragma unroll
    for (int j = 0; j < 4; ++j) outl[ty*4 + i][tx*4 + j] = acc[i][j];
  __syncthreads();
  if (t < 64) {
    float s = 0.f;
    #pragma unroll
    for (int d = 0; d < 64; ++d) { float v = outl[t][d]; s += v * v; }
    nrm[t] = 1.f / sqrtf(s);
  }
  __syncthreads();
  {
    const int n = t >> 2, dg = (t & 3) * 16;
    #pragma unroll
    for (int j = 0; j < 16; ++j)
      o2[(size_t)(n0 + n) * OUTF + h * 64 + dg + j] = outl[n][dg + j] * nrm[n];
  }
}

// ------- K8: LayerNorm over 1024 features ----------------------------------
__global__ __launch_bounds__(256) void k_ln(const float* __restrict__ o2,
    const float* __restrict__ lnw, const float* __restrict__ lnb, float* __restrict__ out) {
  const int n = blockIdx.x, t = threadIdx.x;
  __shared__ float red[4];
  float4 v = *(const float4*)&o2[(size_t)n * OUTF + t * 4];
  float s = v.x + v.y + v.z + v.w;
  const int lane = t & 63, wid = t >> 6;
  #pragma unroll
  for (int off = 32; off; off >>= 1) s += __shfl_down(s, off);
  if (lane == 0) red[wid] = s;
  __syncthreads();
  const float mu = (red[0] + red[1] + red[2] + red[3]) * (1.f / 1024.f);
  float4 d = {v.x - mu, v.y - mu, v.z - mu, v.w - mu};
  float s2 = d.x*d.x + d.y*d.y + d.z*d.z + d.w*d.w;
  #pragma unroll
  for (int off = 32; off; off >>= 1) s2 += __shfl_down(s2, off);
  __syncthreads();
  if (lane == 0) red[wid] = s2;
  __syncthreads();
  const float var = (red[0] + red[1] + red[2] + red[3]) * (1.f / 1024.f);
  const float inv = 1.f / sqrtf(var + 1e-5f);
  float4 w = *(const float4*)&lnw[t * 4];
  float4 b = *(const float4*)&lnb[t * 4];
  float4 o = { d.x*inv*w.x + b.x, d.y*inv*w.y + b.y,
               d.z*inv*w.z + b.z, d.w*inv*w.w + b.w };
  *(float4*)&out[(size_t)n * OUTF + t * 4] = o;
}

extern "C" void kernel_launch(void* const* d_in, const int* in_sizes, int n_in,
                              void* d_out, int out_size, void* d_ws, size_t ws_size,
                              hipStream_t stream) {
  (void)in_sizes; (void)n_in; (void)out_size;
  const float* x    = (const float*)d_in[0];
  const float* Wq   = (const float*)d_in[1];
  const float* bq   = (const float*)d_in[2];
  const float* bp   = (const float*)d_in[3];
  const float* binv = (const float*)d_in[4];
  const float* wm   = (const float*)d_in[5];
  const float* lnw  = (const float*)d_in[6];
  const float* lnb  = (const float*)d_in[7];
  float* outp = (float*)d_out;

  char* ws = (char*)d_ws;
  size_t off = 0;
  auto carve = [&](size_t bytes) -> char* {
    char* p = ws + off;
    off += (bytes + 255) & ~(size_t)255;
    return p;
  };
  float*       q       = (float*)      carve((size_t)NTOK * OUTF * 4);
  signed char* code_i8 = (signed char*)carve((size_t)NH * NTOK * BDIM);
  unsigned*    wpk     = (unsigned*)   carve((size_t)NH * NMEM * NWRD * 4);
  signed char* w_i8    = (signed char*)carve((size_t)NH * NMEM * BDIM);
  float*       bT      = (float*)      carve((size_t)NH * BDIM * DH * 4);
  float*       o2      = (float*)      carve((size_t)NTOK * OUTF * 4);
  const size_t fixed = off;
  const size_t per = ((size_t)BDIM * NMEM * 2 + 256)    // wt
                   + ((size_t)NTOK * NMEM * 2 + 256)    // simb/attn (aliased)
                   + ((size_t)BDIM * NTOK * 4 + 256);   // o1t
  int G = 16;
  while (G > 1 && fixed + (size_t)G * per > ws_size) G >>= 1;
  unsigned short* wt   = (unsigned short*)carve((size_t)G * BDIM * NMEM * 2);
  short*          simb = (short*)         carve((size_t)G * NTOK * NMEM * 2);
  float*          o1t  = (float*)         carve((size_t)G * BDIM * NTOK * 4);
  const int gshift = __builtin_ctz(G);

  k_qgemm<<<dim3(16, 16), 256, 0, stream>>>(x, Wq, bq, q);
  k_code <<<dim3(64, 16), 256, 0, stream>>>(q, bp, code_i8);
  k_packw<<<dim3(NH * NMEM / 4), 256, 0, stream>>>(wm, wpk, w_i8);
  k_binT <<<dim3(8, 16), 256, 0, stream>>>(binv, bT);
  for (int h0 = 0; h0 < NH; h0 += G) {
    k_wt    <<<dim3(32, 8, G), 256, 0, stream>>>(wpk, wt, h0);
    k_sim   <<<dim3(32 * G),   512, 0, stream>>>(code_i8, w_i8, simb, h0, G - 1, gshift);
    k_stageF<<<dim3(32 * G),   512, 0, stream>>>((const unsigned short*)simb, wt, o1t, G - 1, gshift);
    k_proj  <<<dim3(16, G),    256, 0, stream>>>(o1t, bT, o2, h0);
  }
  k_ln<<<dim3(NTOK), 256, 0, stream>>>(o2, lnw, lnb, outp);
}

// Round 13
// 738.307 us; speedup vs baseline: 1.3832x; 1.0277x over previous
//
#include <hip/hip_runtime.h>
#include <hip/hip_fp16.h>

#define NTOK 1024
#define INF  1024
#define NH   16
#define DH   64
#define BDIM 512
#define NMEM 8192
#define OUTF 1024
#define NWRD 16   // 512 bits = 16 u32

typedef _Float16 f16x8 __attribute__((ext_vector_type(8)));
typedef float    f32x4 __attribute__((ext_vector_type(4)));
typedef int      i32x4 __attribute__((ext_vector_type(4)));

#define GLOAD16(G, L) __builtin_amdgcn_global_load_lds( \
    (const __attribute__((address_space(1))) unsigned int*)(G), \
    (__attribute__((address_space(3))) unsigned int*)(L), 16, 0, 0)

// score/TEMP * log2(e):  cos(pi/2*(1-s/512)) == sin(pi/2 * s/512), s = count
__device__ inline float score2(float s) {
  return 144.2695040889f * __sinf(s * 0.0030679615757712823f);
}

// ---------------- K1: q = x @ Wq^T + bq (f32, 64x64 tile) ----------------
__global__ __launch_bounds__(256) void k_qgemm(const float* __restrict__ x,
    const float* __restrict__ Wq, const float* __restrict__ bq, float* __restrict__ q) {
  __shared__ float As[64][17];
  __shared__ float Bs[64][17];
  const int tx = threadIdx.x & 15, ty = threadIdx.x >> 4;
  const int n0 = blockIdx.y * 64, o0 = blockIdx.x * 64;
  const int r = threadIdx.x >> 2, c4 = (threadIdx.x & 3) * 4;
  float acc[4][4] = {};
  for (int k0 = 0; k0 < INF; k0 += 16) {
    float4 av = *(const float4*)&x[(size_t)(n0 + r) * INF + k0 + c4];
    float4 bv = *(const float4*)&Wq[(size_t)(o0 + r) * INF + k0 + c4];
    __syncthreads();               // prev compute done before LDS overwrite
    As[r][c4+0] = av.x; As[r][c4+1] = av.y; As[r][c4+2] = av.z; As[r][c4+3] = av.w;
    Bs[r][c4+0] = bv.x; Bs[r][c4+1] = bv.y; Bs[r][c4+2] = bv.z; Bs[r][c4+3] = bv.w;
    __syncthreads();
    #pragma unroll
    for (int kk = 0; kk < 16; ++kk) {
      float a[4], b[4];
      #pragma unroll
      for (int i = 0; i < 4; ++i) a[i] = As[ty*4+i][kk];
      #pragma unroll
      for (int j = 0; j < 4; ++j) b[j] = Bs[tx*4+j][kk];
      #pragma unroll
      for (int i = 0; i < 4; ++i)
        #pragma unroll
        for (int j = 0; j < 4; ++j) acc[i][j] += a[i] * b[j];
    }
  }
  #pragma unroll
  for (int i = 0; i < 4; ++i) {
    const int row = n0 + ty*4 + i;
    #pragma unroll
    for (int j = 0; j < 4; ++j) {
      const int col = o0 + tx*4 + j;
      q[(size_t)row * OUTF + col] = acc[i][j] + bq[col];
    }
  }
}

// ---------------- K2: code_i8 = sign(q . bin_proj) as +-1 i8 ---------------
// norm of q doesn't change sign -> skip normalization entirely
__global__ __launch_bounds__(256) void k_code(const float* __restrict__ q,
    const float* __restrict__ bp, signed char* __restrict__ code_i8) {
  const int h = blockIdx.y, n0 = blockIdx.x * 16;
  __shared__ float ql[16][68];
  const int t = threadIdx.x;
  {
    const int r = t >> 4, c = (t & 15) * 4;
    float4 v = *(const float4*)&q[(size_t)(n0 + r) * OUTF + h * 64 + c];
    ql[r][c] = v.x; ql[r][c+1] = v.y; ql[r][c+2] = v.z; ql[r][c+3] = v.w;
  }
  __syncthreads();
  #pragma unroll
  for (int bb = 0; bb < 512; bb += 256) {
    const int b = bb + t;
    float bpv[64];
    const float4* src = (const float4*)&bp[((size_t)h * BDIM + b) * 64];
    #pragma unroll
    for (int j = 0; j < 16; ++j) {
      float4 v = src[j];
      bpv[j*4] = v.x; bpv[j*4+1] = v.y; bpv[j*4+2] = v.z; bpv[j*4+3] = v.w;
    }
    for (int n = 0; n < 16; ++n) {
      float dot = 0.f;
      #pragma unroll
      for (int d = 0; d < 64; ++d) dot += bpv[d] * ql[n][d];
      code_i8[((size_t)h * NTOK + n0 + n) * BDIM + b] = dot > 0.f ? 1 : -1;
    }
  }
}

// -------- K3: weight_matrix -> sign bits (for k_wt) AND +-1 i8 -------------
// w_i8 is written CHUNK-SWIZZLED: 16B chunk c of row m lands at physical
// chunk p=(c&~7)|((c&7)^(m&7)) so k_sim's linear global_load_lds staging +
// swizzled ds_read_b128 is bank-conflict-free (rule: swizzle both sides).
__global__ __launch_bounds__(256) void k_packw(const float* __restrict__ w,
    unsigned* __restrict__ wp, signed char* __restrict__ w_i8) {
  const int row  = blockIdx.x * 4 + (threadIdx.x >> 6);
  const int lane = threadIdx.x & 63;
  const float* src = w + (size_t)row * BDIM;
  unsigned my = 0;
  #pragma unroll
  for (int kk = 0; kk < 8; ++kk) {
    float v = src[kk * 64 + lane];
    const int c = kk * 4 + (lane >> 4);
    const int p = (c & ~7) | ((c & 7) ^ (row & 7));
    w_i8[(size_t)row * BDIM + p * 16 + (lane & 15)] = v > 0.f ? 1 : -1;
    unsigned long long m = __ballot(v > 0.f);
    if ((lane >> 1) == kk) my = (lane & 1) ? (unsigned)(m >> 32) : (unsigned)m;
  }
  if (lane < 16) wp[(size_t)row * NWRD + lane] = my;
}

// ---------------- K3b: transpose bin_inv [h][d][b] -> binT [h][b][d] -------
__global__ __launch_bounds__(256) void k_binT(const float* __restrict__ binv,
                                              float* __restrict__ bT) {
  const int h = blockIdx.y, b0 = blockIdx.x * 64;
  __shared__ float tl[64][65];
  const int t = threadIdx.x;
  #pragma unroll
  for (int i = 0; i < 4; ++i) {
    int fi = t + 256 * i;
    int d = fi >> 4, b = (fi & 15) * 4;
    float4 v = *(const float4*)&binv[((size_t)h * DH + d) * BDIM + b0 + b];
    tl[d][b] = v.x; tl[d][b+1] = v.y; tl[d][b+2] = v.z; tl[d][b+3] = v.w;
  }
  __syncthreads();
  #pragma unroll
  for (int i = 0; i < 4; ++i) {
    int fo = t + 256 * i;
    int bb = fo >> 4, dd = (fo & 15) * 4;
    float4 v = { tl[dd][bb], tl[dd+1][bb], tl[dd+2][bb], tl[dd+3][bb] };
    *(float4*)&bT[((size_t)h * BDIM + b0 + bb) * DH + dd] = v;
  }
}

// ------- K4: expand bits -> f16 wt [hg][b][m] (+-1), PRE-SWIZZLED ----------
// Within each 128B (64-m) window, 16B chunk g stores logical chunk g^(b&7),
// so stageF's linear global_load_lds + swizzled ds_read are conflict-free.
__global__ __launch_bounds__(256) void k_wt(const unsigned* __restrict__ wp,
    unsigned short* __restrict__ wt, int h0) {
  const int hg = blockIdx.z, h = h0 + hg;
  const int b0 = blockIdx.y * 64, m0 = blockIdx.x * 256;
  __shared__ unsigned bits[256][2];
  const int t = threadIdx.x;
  const unsigned* src = wp + (size_t)(h * NMEM + m0 + t) * NWRD + (b0 >> 5);
  bits[t][0] = src[0]; bits[t][1] = src[1];
  __syncthreads();
  const int b = t >> 2, ms = (t & 3) * 64;
  const int wd = b >> 5, sh = b & 31;
  const int bx7 = b & 7;
  unsigned short* dst = wt + ((size_t)hg * BDIM + b0 + b) * NMEM + m0 + ms;
  #pragma unroll
  for (int g = 0; g < 8; ++g) {
    const int pg = g ^ bx7;
    const int j = ms + g * 8;
    ushort4 v0, v1;
    v0.x = ((bits[j+0][wd] >> sh) & 1) ? 0x3C00 : 0xBC00;
    v0.y = ((bits[j+1][wd] >> sh) & 1) ? 0x3C00 : 0xBC00;
    v0.z = ((bits[j+2][wd] >> sh) & 1) ? 0x3C00 : 0xBC00;
    v0.w = ((bits[j+3][wd] >> sh) & 1) ? 0x3C00 : 0xBC00;
    v1.x = ((bits[j+4][wd] >> sh) & 1) ? 0x3C00 : 0xBC00;
    v1.y = ((bits[j+5][wd] >> sh) & 1) ? 0x3C00 : 0xBC00;
    v1.z = ((bits[j+6][wd] >> sh) & 1) ? 0x3C00 : 0xBC00;
    v1.w = ((bits[j+7][wd] >> sh) & 1) ? 0x3C00 : 0xBC00;
    *(ushort4*)&dst[pg * 8]     = v0;
    *(ushort4*)&dst[pg * 8 + 4] = v1;
  }
}

// ------- K5: two-pass sim+exp -> attn f16 (no i16 intermediate) ------------
// Pass 1: stage w_i8 (GLOAD) + i8 MFMA + running rowmax. ZERO stores -> the
//   per-tile barrier drains pure DMA.
// Pass 2: same staging + MFMA; p = exp2(score2(s)-score2(smax)) via direct
//   __sinf (no LDS table gathers); p -> padded LDS tile; coalesced 16B/thread
//   global stores (pre-swizzled chunk c^(row&7) for stageF) issued while the
//   NEXT tile's DMA is in flight.
// Proven R10/R12 2-barrier skeleton; no stage-ahead (that schedule raced).
// Softmax 1/Z cancels in the later per-head L2-normalize -> numerator only.
__global__ __launch_bounds__(512, 2) void k_sim(const signed char* __restrict__ code_i8,
    const signed char* __restrict__ w_i8, unsigned short* __restrict__ attn,
    int h0, int gmask, int gshift) {
  const int bid = (int)blockIdx.x;
  const int hg = bid & gmask, h = h0 + hg;      // XCD = bid%8 = h%8 (convoy)
  const int n0 = (bid >> gshift) * 32;
  const int t = threadIdx.x, lane = t & 63, wid = t >> 6;
  __shared__ __align__(16) signed char Bls[128 * 512];   // 64KB B tile
  __shared__ __align__(16) _Float16 Pls[32][136];        // 8.5KB, padded
  __shared__ int smaxl[32];
  if (t < 32) smaxl[t] = -(1 << 30);
  const int rg = wid >> 2, mg = wid & 3;
  // A frags: row = n0 + rg*16 + (lane&15), k = kk*64 + (lane>>4)*16
  i32x4 afrag[8];
  #pragma unroll
  for (int kk = 0; kk < 8; ++kk)
    afrag[kk] = *(const i32x4*)(code_i8 +
        ((size_t)h * NTOK + n0 + rg * 16 + (lane & 15)) * BDIM +
        kk * 64 + (lane >> 4) * 16);
  const signed char* wb = w_i8 + (size_t)h * NMEM * BDIM + (size_t)t * 16;
  signed char* const d0 = &Bls[wid * 1024];     // wave-uniform LDS base
  int vmax[4] = {-(1 << 30), -(1 << 30), -(1 << 30), -(1 << 30)};
  // ---------------- PASS 1: rowmax only (no stores) ----------------
  for (int tile = 0; tile < 64; ++tile) {       // 128 m per tile
    const signed char* s = wb + (size_t)tile * 128 * BDIM;
    __syncthreads();                  // previous tile fully consumed
    #pragma unroll
    for (int seg = 0; seg < 8; ++seg)
      GLOAD16(s + seg * 8192, d0 + seg * 8192);
    __syncthreads();                  // drains vmcnt -> tile ready
    #pragma unroll
    for (int msub = 0; msub < 2; ++msub) {
      const signed char* bls = &Bls[(mg * 32 + msub * 16 + (lane & 15)) * 512];
      i32x4 acc = {};
      #pragma unroll
      for (int kk = 0; kk < 8; ++kk) {
        const int c = kk * 4 + (lane >> 4);
        const int p = (c & ~7) | ((c & 7) ^ (lane & 7));
        i32x4 b = *(const i32x4*)(bls + p * 16);
        acc = __builtin_amdgcn_mfma_i32_16x16x64_i8(afrag[kk], b, acc, 0, 0, 0);
      }
      #pragma unroll
      for (int j = 0; j < 4; ++j) vmax[j] = max(vmax[j], acc[j]);
    }
  }
  #pragma unroll
  for (int j = 0; j < 4; ++j) {
    int v = vmax[j];
    #pragma unroll
    for (int s = 1; s < 16; s <<= 1) v = max(v, __shfl_xor(v, s));
    if ((lane & 15) == 0)
      atomicMax(&smaxl[rg * 16 + (lane >> 4) * 4 + j], v);
  }
  __syncthreads();                     // smaxl final
  float sm[4];
  #pragma unroll
  for (int j = 0; j < 4; ++j)
    sm[j] = score2((float)smaxl[rg * 16 + (lane >> 4) * 4 + j]);
  // store-phase decode (per thread): one 16B chunk of one Pls row
  const int srow = t >> 4, sg = t & 15;
  unsigned short* const sdst = attn + ((size_t)hg * NTOK + n0 + srow) * NMEM;
  const int spc = ((sg & 7) ^ (srow & 7)) * 8 + (sg >> 3) * 64;  // swizzled
  // ---------------- PASS 2: recompute + exp -> attn ----------------
  for (int tile = 0; tile < 64; ++tile) {
    const signed char* s = wb + (size_t)tile * 128 * BDIM;
    __syncthreads();                  // Bls consumed, Pls(t-1) written
    #pragma unroll
    for (int seg = 0; seg < 8; ++seg)
      GLOAD16(s + seg * 8192, d0 + seg * 8192);
    if (tile > 0) {                   // store Pls(t-1) while DMA in flight
      f16x8 pv = *(const f16x8*)&Pls[srow][sg * 8];
      *(f16x8*)(sdst + (size_t)(tile - 1) * 128 + spc) = pv;
    }
    __syncthreads();                  // DMA done + Pls reads done
    #pragma unroll
    for (int msub = 0; msub < 2; ++msub) {
      const signed char* bls = &Bls[(mg * 32 + msub * 16 + (lane & 15)) * 512];
      i32x4 acc = {};
      #pragma unroll
      for (int kk = 0; kk < 8; ++kk) {
        const int c = kk * 4 + (lane >> 4);
        const int p = (c & ~7) | ((c & 7) ^ (lane & 7));
        i32x4 b = *(const i32x4*)(bls + p * 16);
        acc = __builtin_amdgcn_mfma_i32_16x16x64_i8(afrag[kk], b, acc, 0, 0, 0);
      }
      const int col = mg * 32 + msub * 16 + (lane & 15);
      #pragma unroll
      for (int j = 0; j < 4; ++j) {
        const int r0 = rg * 16 + (lane >> 4) * 4 + j;
        float pr = exp2f(score2((float)acc[j]) - sm[j]);
        Pls[r0][col] = (_Float16)pr;
      }
    }
  }
  __syncthreads();                     // last Pls written
  {                                    // epilogue: store tile 63
    f16x8 pv = *(const f16x8*)&Pls[srow][sg * 8];
    *(f16x8*)(sdst + (size_t)63 * 128 + spc) = pv;
  }
}

// ------- K6: o1^T = (attn @ wt)^T, pure f16 MFMA GEMM, 128x128 tile --------
// Both operands pre-swizzled in global; linear global_load_lds staging;
// XOR-deswizzled ds_read_b128.
__global__ __launch_bounds__(512, 2) void k_stageF(const unsigned short* __restrict__ attn,
    const unsigned short* __restrict__ wt, float* __restrict__ o1t,
    int gmask, int gshift) {
  __shared__ __align__(16) _Float16 Al[128][64];
  __shared__ __align__(16) _Float16 Bl[128][64];
  const int wg = (int)blockIdx.x;
  const int hg = wg & gmask;                   // XCD = wg%8 = hg%8
  const int rest = wg >> gshift;
  const int nt = rest & 7, bt = rest >> 3;
  const int n0 = nt * 128, b0 = bt * 128;
  const int t = threadIdx.x;
  const int lane = t & 63, wid = t >> 6;
  const int wm = wid >> 2, wn = wid & 3;
  f32x4 acc[4][2];
  #pragma unroll
  for (int i = 0; i < 4; ++i)
    #pragma unroll
    for (int j = 0; j < 2; ++j) acc[i][j] = (f32x4){0.f, 0.f, 0.f, 0.f};

  const unsigned short* ag = attn + ((size_t)hg * NTOK + n0 + 16*wid + (lane >> 3)) * NMEM + (lane & 7) * 8;
  const unsigned short* bg = wt   + ((size_t)hg * BDIM + b0 + 16*wid + (lane >> 3)) * NMEM + (lane & 7) * 8;
  _Float16* al0 = &Al[16 * wid][0];            // wave-uniform LDS bases
  _Float16* bl0 = &Bl[16 * wid][0];

  for (int k0 = 0; k0 < NMEM; k0 += 64) {
    __syncthreads();                    // previous tile fully consumed
    GLOAD16(ag + k0,            al0);
    GLOAD16(ag + k0 + 8 * NMEM, al0 + 8 * 64);
    GLOAD16(bg + k0,            bl0);
    GLOAD16(bg + k0 + 8 * NMEM, bl0 + 8 * 64);
    __syncthreads();                    // drains vmcnt -> tile ready
    #pragma unroll
    for (int kk = 0; kk < 64; kk += 32) {
      const int phys = (((kk >> 3) + (lane >> 4)) ^ (lane & 7)) * 8;
      f16x8 af[4], bf[2];
      #pragma unroll
      for (int fm = 0; fm < 4; ++fm)
        af[fm] = *(const f16x8*)&Al[wm*64 + fm*16 + (lane & 15)][phys];
      #pragma unroll
      for (int fn = 0; fn < 2; ++fn)
        bf[fn] = *(const f16x8*)&Bl[wn*32 + fn*16 + (lane & 15)][phys];
      #pragma unroll
      for (int fm = 0; fm < 4; ++fm)
        #pragma unroll
        for (int fn = 0; fn < 2; ++fn)
          acc[fm][fn] = __builtin_amdgcn_mfma_f32_16x16x32_f16(af[fm], bf[fn], acc[fm][fn], 0, 0, 0);
    }
  }
  #pragma unroll
  for (int fm = 0; fm < 4; ++fm) {
    const int rowb = n0 + wm*64 + fm*16 + (lane >> 4) * 4;   // C: row=(l>>4)*4+reg
    #pragma unroll
    for (int fn = 0; fn < 2; ++fn) {
      const int col = b0 + wn*32 + fn*16 + (lane & 15);      // C: col=l&15
      *(f32x4*)&o1t[((size_t)hg * BDIM + col) * NTOK + rowb] = acc[fm][fn];
    }
  }
}

// ------- K7: out[n][h*64+d] = normalize_d( o1 . bin_inv ) ------------------
__global__ __launch_bounds__(256) void k_proj(const float* __restrict__ o1t,
    const float* __restrict__ bT, float* __restrict__ o2, int h0) {
  const int hg = blockIdx.y, h = h0 + hg;
  const int n0 = blockIdx.x * 64;
  __shared__ float bl[128][68];
  __shared__ float ol[128][68];
  __shared__ float outl[64][68];
  __shared__ float nrm[64];
  const int t = threadIdx.x;
  const int tx = t & 15, ty = t >> 4;
  float acc[4][4] = {};
  for (int c = 0; c < 4; ++c) {
    const int bb0 = c * 128;
    __syncthreads();
    #pragma unroll
    for (int i = 0; i < 8; ++i) {
      int fi = t + 256 * i;
      int rr = fi >> 4, cc = (fi & 15) * 4;
      *(float4*)&bl[rr][cc] = *(const float4*)&bT[((size_t)h * BDIM + bb0 + rr) * DH + cc];
      *(float4*)&ol[rr][cc] = *(const float4*)&o1t[((size_t)hg * BDIM + bb0 + rr) * NTOK + n0 + cc];
    }
    __syncthreads();
    for (int bb = 0; bb < 128; ++bb) {
      float4 bd = *(const float4*)&bl[bb][tx * 4];
      float4 on = *(const float4*)&ol[bb][ty * 4];
      float ai[4] = {on.x, on.y, on.z, on.w};
      float bj[4] = {bd.x, bd.y, bd.z, bd.w};
      #pragma unroll
      for (int i = 0; i < 4; ++i)
        #pragma unroll
        for (int j = 0; j < 4; ++j) acc[i][j] += ai[i] * bj[j];
    }
  }
  __syncthreads();
  #pragma unroll
  for (int i = 0; i < 4; ++i)
    #pragma unroll
    for (int j = 0; j < 4; ++j) outl[ty*4 + i][tx*4 + j] = acc[i][j];
  __syncthreads();
  if (t < 64) {
    float s = 0.f;
    #pragma unroll
    for (int d = 0; d < 64; ++d) { float v = outl[t][d]; s += v * v; }
    nrm[t] = 1.f / sqrtf(s);
  }
  __syncthreads();
  {
    const int n = t >> 2, dg = (t & 3) * 16;
    #pragma unroll
    for (int j = 0; j < 16; ++j)
      o2[(size_t)(n0 + n) * OUTF + h * 64 + dg + j] = outl[n][dg + j] * nrm[n];
  }
}

// ------- K8: LayerNorm over 1024 features ----------------------------------
__global__ __launch_bounds__(256) void k_ln(const float* __restrict__ o2,
    const float* __restrict__ lnw, const float* __restrict__ lnb, float* __restrict__ out) {
  const int n = blockIdx.x, t = threadIdx.x;
  __shared__ float red[4];
  float4 v = *(const float4*)&o2[(size_t)n * OUTF + t * 4];
  float s = v.x + v.y + v.z + v.w;
  const int lane = t & 63, wid = t >> 6;
  #pragma unroll
  for (int off = 32; off; off >>= 1) s += __shfl_down(s, off);
  if (lane == 0) red[wid] = s;
  __syncthreads();
  const float mu = (red[0] + red[1] + red[2] + red[3]) * (1.f / 1024.f);
  float4 d = {v.x - mu, v.y - mu, v.z - mu, v.w - mu};
  float s2 = d.x*d.x + d.y*d.y + d.z*d.z + d.w*d.w;
  #pragma unroll
  for (int off = 32; off; off >>= 1) s2 += __shfl_down(s2, off);
  __syncthreads();
  if (lane == 0) red[wid] = s2;
  __syncthreads();
  const float var = (red[0] + red[1] + red[2] + red[3]) * (1.f / 1024.f);
  const float inv = 1.f / sqrtf(var + 1e-5f);
  float4 w = *(const float4*)&lnw[t * 4];
  float4 b = *(const float4*)&lnb[t * 4];
  float4 o = { d.x*inv*w.x + b.x, d.y*inv*w.y + b.y,
               d.z*inv*w.z + b.z, d.w*inv*w.w + b.w };
  *(float4*)&out[(size_t)n * OUTF + t * 4] = o;
}

extern "C" void kernel_launch(void* const* d_in, const int* in_sizes, int n_in,
                              void* d_out, int out_size, void* d_ws, size_t ws_size,
                              hipStream_t stream) {
  (void)in_sizes; (void)n_in; (void)out_size;
  const float* x    = (const float*)d_in[0];
  const float* Wq   = (const float*)d_in[1];
  const float* bq   = (const float*)d_in[2];
  const float* bp   = (const float*)d_in[3];
  const float* binv = (const float*)d_in[4];
  const float* wm   = (const float*)d_in[5];
  const float* lnw  = (const float*)d_in[6];
  const float* lnb  = (const float*)d_in[7];
  float* outp = (float*)d_out;

  char* ws = (char*)d_ws;
  size_t off = 0;
  auto carve = [&](size_t bytes) -> char* {
    char* p = ws + off;
    off += (bytes + 255) & ~(size_t)255;
    return p;
  };
  float*       q       = (float*)      carve((size_t)NTOK * OUTF * 4);
  signed char* code_i8 = (signed char*)carve((size_t)NH * NTOK * BDIM);
  unsigned*    wpk     = (unsigned*)   carve((size_t)NH * NMEM * NWRD * 4);
  signed char* w_i8    = (signed char*)carve((size_t)NH * NMEM * BDIM);
  float*       bT      = (float*)      carve((size_t)NH * BDIM * DH * 4);
  float*       o2      = (float*)      carve((size_t)NTOK * OUTF * 4);
  const size_t fixed = off;
  const size_t per = ((size_t)BDIM * NMEM * 2 + 256)    // wt
                   + ((size_t)NTOK * NMEM * 2 + 256)    // attn f16
                   + ((size_t)BDIM * NTOK * 4 + 256);   // o1t
  int G = 16;
  while (G > 1 && fixed + (size_t)G * per > ws_size) G >>= 1;
  unsigned short* wt   = (unsigned short*)carve((size_t)G * BDIM * NMEM * 2);
  unsigned short* attn = (unsigned short*)carve((size_t)G * NTOK * NMEM * 2);
  float*          o1t  = (float*)         carve((size_t)G * BDIM * NTOK * 4);
  const int gshift = __builtin_ctz(G);

  k_qgemm<<<dim3(16, 16), 256, 0, stream>>>(x, Wq, bq, q);
  k_code <<<dim3(64, 16), 256, 0, stream>>>(q, bp, code_i8);
  k_packw<<<dim3(NH * NMEM / 4), 256, 0, stream>>>(wm, wpk, w_i8);
  k_binT <<<dim3(8, 16), 256, 0, stream>>>(binv, bT);
  for (int h0 = 0; h0 < NH; h0 += G) {
    k_wt    <<<dim3(32, 8, G), 256, 0, stream>>>(wpk, wt, h0);
    k_sim   <<<dim3(32 * G),   512, 0, stream>>>(code_i8, w_i8, attn, h0, G - 1, gshift);
    k_stageF<<<dim3(32 * G),   512, 0, stream>>>(attn, wt, o1t, G - 1, gshift);
    k_proj  <<<dim3(16, G),    256, 0, stream>>>(o1t, bT, o2, h0);
  }
  k_ln<<<dim3(NTOK), 256, 0, stream>>>(o2, lnw, lnb, outp);
}